// Round 1
// baseline (3164.214 us; speedup 1.0000x reference)
//
#include <hip/hip_runtime.h>

#define NNODES 500000
#define NEDGES 8000000
#define NGRAPHS 512
#define NFEAT 128
#define NHID 128
#define NFILT 8
#define ODIM 64
#define BN_EPS 1e-5f

// ---------------- Kernel 1: fv = relu(x@W1+b1)@W2 + b2  [N,8] ----------------
// block = 128 threads (one per hidden column), 32 nodes per block.
__global__ __launch_bounds__(128) void k_filt(
    const float* __restrict__ x, const float* __restrict__ W1,
    const float* __restrict__ b1, const float* __restrict__ W2,
    const float* __restrict__ b2, float* __restrict__ fv) {
  __shared__ __align__(16) float xs[32][NFEAT];    // 16 KB, reused as h-tile
  __shared__ __align__(16) float w2t[NFILT][NHID]; // 4 KB (W2 transposed)
  const int t = threadIdx.x;
  const int base = blockIdx.x * 32;

  // stage x tile (coalesced float4)
  const float4* xg = (const float4*)(x + (size_t)base * NFEAT);
  float4* xs4 = (float4*)&xs[0][0];
#pragma unroll
  for (int r = 0; r < 8; ++r) xs4[t + r * 128] = xg[t + r * 128];
#pragma unroll
  for (int f = 0; f < NFILT; ++f) w2t[f][t] = W2[t * NFILT + f];
  __syncthreads();

  // GEMM1: thread t owns hidden column j=t, 32 node accumulators
  float acc[32];
#pragma unroll
  for (int i = 0; i < 32; ++i) acc[i] = 0.f;
  for (int k = 0; k < NFEAT; k += 4) {
    float w0 = W1[(k + 0) * NHID + t];
    float w1 = W1[(k + 1) * NHID + t];
    float w2 = W1[(k + 2) * NHID + t];
    float w3 = W1[(k + 3) * NHID + t];
#pragma unroll
    for (int i = 0; i < 32; ++i) {
      float4 xv = *(const float4*)&xs[i][k];  // broadcast LDS read
      acc[i] = fmaf(xv.x, w0, acc[i]);
      acc[i] = fmaf(xv.y, w1, acc[i]);
      acc[i] = fmaf(xv.z, w2, acc[i]);
      acc[i] = fmaf(xv.w, w3, acc[i]);
    }
  }
  const float bb = b1[t];
  __syncthreads();  // xs fully consumed; reuse as h tile
#pragma unroll
  for (int i = 0; i < 32; ++i) xs[i][t] = fmaxf(acc[i] + bb, 0.f);
  __syncthreads();

  // GEMM2: 32 nodes x 8 filt = 256 outputs; 2 per thread
#pragma unroll
  for (int rep = 0; rep < 2; ++rep) {
    int idx = t + rep * 128;
    int i = idx >> 3, f = idx & 7;
    float a = b2[f];
    for (int k = 0; k < NHID; k += 4) {
      float4 hv = *(const float4*)&xs[i][k];
      float4 wv = *(const float4*)&w2t[f][k];
      a = fmaf(hv.x, wv.x, a);
      a = fmaf(hv.y, wv.y, a);
      a = fmaf(hv.z, wv.z, a);
      a = fmaf(hv.w, wv.w, a);
    }
    fv[(size_t)(base + i) * NFILT + f] = a;
  }
}

// ------- Kernel 2: persistence pairs + y = relu(x16@W0+b0), segsum1 -------
// block = 256 = 4 node-groups x 64 lanes; lane j = output dim j.
__global__ __launch_bounds__(256) void k_pairs(
    const float* __restrict__ fv, const int* __restrict__ edge_index,
    const int* __restrict__ didx, const int* __restrict__ batch,
    const float* __restrict__ W0, const float* __restrict__ b0,
    float* __restrict__ y, float* __restrict__ sums1, int* __restrict__ cnt) {
  __shared__ float w0s[16 * 64];
  __shared__ float b0s[64];
  const int t = threadIdx.x;
  for (int i = t; i < 16 * 64; i += 256) w0s[i] = W0[i];
  if (t < 64) b0s[t] = b0[t];
  __syncthreads();

  const int grp = t >> 6, j = t & 63;
  const int n = blockIdx.x * 4 + grp;  // 125000 blocks * 4 = 500000 exact

  const int de = didx[n];
  const int u = edge_index[de];
  const int v = edge_index[NEDGES + de];
  float4 b0v = *(const float4*)&fv[(size_t)n * 8];
  float4 b1v = *(const float4*)&fv[(size_t)n * 8 + 4];
  float4 u0v = *(const float4*)&fv[(size_t)u * 8];
  float4 u1v = *(const float4*)&fv[(size_t)u * 8 + 4];
  float4 v0v = *(const float4*)&fv[(size_t)v * 8];
  float4 v1v = *(const float4*)&fv[(size_t)v * 8 + 4];

  float xx[16];
  xx[0] = b0v.x;  xx[2] = b0v.y;  xx[4] = b0v.z;  xx[6] = b0v.w;
  xx[8] = b1v.x;  xx[10] = b1v.y; xx[12] = b1v.z; xx[14] = b1v.w;
  xx[1]  = fmaxf(u0v.x, v0v.x); xx[3]  = fmaxf(u0v.y, v0v.y);
  xx[5]  = fmaxf(u0v.z, v0v.z); xx[7]  = fmaxf(u0v.w, v0v.w);
  xx[9]  = fmaxf(u1v.x, v1v.x); xx[11] = fmaxf(u1v.y, v1v.y);
  xx[13] = fmaxf(u1v.z, v1v.z); xx[15] = fmaxf(u1v.w, v1v.w);

  float a = b0s[j];
#pragma unroll
  for (int k = 0; k < 16; ++k) a = fmaf(xx[k], w0s[k * 64 + j], a);
  a = fmaxf(a, 0.f);
  y[(size_t)n * 64 + j] = a;
  const int g = batch[n];
  atomicAdd(&sums1[g * 64 + j], a);
  if (j == 0) atomicAdd(&cnt[g], 1);
}

// ---------- Kernel 3/5: xm = (sums/max(cnt,1)) @ LW  (D = 64 or 128) ----------
template <int D>
__global__ void k_meanlin(const float* __restrict__ sums,
                          const int* __restrict__ cnt,
                          const float* __restrict__ LW,
                          float* __restrict__ xm) {
  __shared__ float m[64];
  const int g = blockIdx.x, t = threadIdx.x;
  const float c = fmaxf((float)cnt[g], 1.f);
  if (t < 64) m[t] = sums[g * 64 + t] / c;
  __syncthreads();
  float a = 0.f;
#pragma unroll
  for (int k = 0; k < 64; ++k) a = fmaf(m[k], LW[k * D + t], a);
  xm[g * D + t] = a;
}

// ---- Kernel 4: deepset1 apply in-place: y = relu(y@g1W+g1b-xm1[g]), segsum2 ----
__global__ __launch_bounds__(256) void k_ds1(
    float* __restrict__ y, const int* __restrict__ batch,
    const float* __restrict__ g1W, const float* __restrict__ g1b,
    const float* __restrict__ xm1, float* __restrict__ sums2) {
  __shared__ float gs[64 * 64];  // 16 KB
  const int t = threadIdx.x;
  for (int i = t; i < 64 * 64; i += 256) gs[i] = g1W[i];
  __syncthreads();
  const int grp = t >> 6, j = t & 63;
  const float bb = g1b[j];
  const int base = blockIdx.x * 32 + grp * 8;
#pragma unroll 1
  for (int ii = 0; ii < 8; ++ii) {
    const int n = base + ii;
    const float yo = y[(size_t)n * 64 + j];
    const int g = batch[n];
    float a = bb - xm1[g * 64 + j];
#pragma unroll
    for (int k = 0; k < 64; ++k)
      a = fmaf(__shfl(yo, k, 64), gs[k * 64 + j], a);
    a = fmaxf(a, 0.f);
    y[(size_t)n * 64 + j] = a;  // in-place (row fully read first)
    atomicAdd(&sums2[g * 64 + j], a);
  }
}

// - Kernel 6: h = relu(z@g2W+g2b-xm2[g]) -> d_out; per-feature sum/sumsq atomics -
__global__ __launch_bounds__(128) void k_ds2(
    const float* __restrict__ z, const int* __restrict__ batch,
    const float* __restrict__ g2W, const float* __restrict__ g2b,
    const float* __restrict__ xm2, float* __restrict__ h,
    float* __restrict__ musum, float* __restrict__ sqsum) {
  __shared__ float gs[64 * 128];  // 32 KB
  const int f = threadIdx.x;
  for (int i = f; i < 64 * 128; i += 128) gs[i] = g2W[i];
  __syncthreads();
  const int base = blockIdx.x * 32;
  const float bb = g2b[f];
  float s = 0.f, q = 0.f;
#pragma unroll 1
  for (int ii = 0; ii < 32; ++ii) {
    const int n = base + ii;
    float a = bb;
    const float4* zr = (const float4*)&z[(size_t)n * 64];
#pragma unroll
    for (int k4 = 0; k4 < 16; ++k4) {
      float4 zv = zr[k4];  // broadcast
      a = fmaf(zv.x, gs[(k4 * 4 + 0) * 128 + f], a);
      a = fmaf(zv.y, gs[(k4 * 4 + 1) * 128 + f], a);
      a = fmaf(zv.z, gs[(k4 * 4 + 2) * 128 + f], a);
      a = fmaf(zv.w, gs[(k4 * 4 + 3) * 128 + f], a);
    }
    const int g = batch[n];
    a -= xm2[g * 128 + f];
    a = fmaxf(a, 0.f);
    h[(size_t)n * 128 + f] = a;
    s += a;
    q = fmaf(a, a, q);
  }
  atomicAdd(&musum[f], s);
  atomicAdd(&sqsum[f], q);
}

// ------- Kernel 7: out = x + (h-mu)*rsqrt(var+eps)*gamma + beta (in-place) -------
__global__ __launch_bounds__(256) void k_bn(
    const float* __restrict__ x, float* hout,
    const float* __restrict__ musum, const float* __restrict__ sqsum,
    const float* __restrict__ gamma, const float* __restrict__ beta) {
  const size_t i = (size_t)blockIdx.x * 256 + threadIdx.x;  // float4 index
  const int f0 = (int)(i & 31) * 4;
  const float invN = 1.f / (float)NNODES;
  float mu[4], sc[4], be[4];
#pragma unroll
  for (int r = 0; r < 4; ++r) {
    float m = musum[f0 + r] * invN;
    float v = sqsum[f0 + r] * invN - m * m;
    sc[r] = rsqrtf(v + BN_EPS) * gamma[f0 + r];
    mu[r] = m;
    be[r] = beta[f0 + r];
  }
  float4 hv = ((const float4*)hout)[i];
  float4 xv = ((const float4*)x)[i];
  float4 o;
  o.x = xv.x + (hv.x - mu[0]) * sc[0] + be[0];
  o.y = xv.y + (hv.y - mu[1]) * sc[1] + be[1];
  o.z = xv.z + (hv.z - mu[2]) * sc[2] + be[2];
  o.w = xv.w + (hv.w - mu[3]) * sc[3] + be[3];
  ((float4*)hout)[i] = o;
}

extern "C" void kernel_launch(void* const* d_in, const int* in_sizes, int n_in,
                              void* d_out, int out_size, void* d_ws,
                              size_t ws_size, hipStream_t stream) {
  const float* x     = (const float*)d_in[0];
  const float* W1    = (const float*)d_in[1];
  const float* b1    = (const float*)d_in[2];
  const float* W2    = (const float*)d_in[3];
  const float* b2    = (const float*)d_in[4];
  const float* W0    = (const float*)d_in[5];
  const float* b0    = (const float*)d_in[6];
  const float* g1W   = (const float*)d_in[7];
  const float* g1b   = (const float*)d_in[8];
  const float* l1W   = (const float*)d_in[9];
  const float* g2W   = (const float*)d_in[10];
  const float* g2b   = (const float*)d_in[11];
  const float* l2W   = (const float*)d_in[12];
  const float* gamma = (const float*)d_in[13];
  const float* beta  = (const float*)d_in[14];
  const int* edge_index = (const int*)d_in[15];
  const int* batch      = (const int*)d_in[16];
  const int* didx       = (const int*)d_in[17];
  float* out = (float*)d_out;

  char* ws = (char*)d_ws;
  float* fv    = (float*)(ws + 0);            // N*8*4  = 16,000,000 B
  float* y     = (float*)(ws + 16000000);     // N*64*4 = 128,000,000 B
  float* sums1 = (float*)(ws + 144000000);    // 131072 B
  float* sums2 = (float*)(ws + 144131072);    // 131072 B
  int*   cnt   = (int*)  (ws + 144262144);    // 2048 B
  float* musum = (float*)(ws + 144264192);    // 512 B
  float* sqsum = (float*)(ws + 144264704);    // 512 B
  float* xm1   = (float*)(ws + 144265216);    // 131072 B
  float* xm2   = (float*)(ws + 144396288);    // 262144 B
  // total = 144,658,432 B

  hipMemsetAsync(ws + 144000000, 0, 265216, stream);  // zero all accumulators

  k_filt<<<NNODES / 32, 128, 0, stream>>>(x, W1, b1, W2, b2, fv);
  k_pairs<<<NNODES / 4, 256, 0, stream>>>(fv, edge_index, didx, batch, W0, b0,
                                          y, sums1, cnt);
  k_meanlin<64><<<NGRAPHS, 64, 0, stream>>>(sums1, cnt, l1W, xm1);
  k_ds1<<<NNODES / 32, 256, 0, stream>>>(y, batch, g1W, g1b, xm1, sums2);
  k_meanlin<128><<<NGRAPHS, 128, 0, stream>>>(sums2, cnt, l2W, xm2);
  k_ds2<<<NNODES / 32, 128, 0, stream>>>(y, batch, g2W, g2b, xm2, out, musum,
                                         sqsum);
  k_bn<<<(NNODES * 128 / 4) / 256, 256, 0, stream>>>(x, out, musum, sqsum,
                                                     gamma, beta);
}

// Round 2
// 1463.382 us; speedup vs baseline: 2.1623x; 2.1623x over previous
//
#include <hip/hip_runtime.h>

#define NNODES 500000
#define NEDGES 8000000
#define NGRAPHS 512
#define NFEAT 128
#define NHID 128
#define NFILT 8
#define ODIM 64
#define BN_EPS 1e-5f
#define NBLK2 3907  // ceil(NNODES/128) blocks for k_ds1/k_ds2/k_pairs

// ---------------- Kernel 1: fv = relu(x@W1+b1)@W2 + b2  [N,8] ----------------
// block 256 threads, 64 nodes/block; 8-node x 4-col register tiles.
__global__ __launch_bounds__(256) void k_filt(
    const float* __restrict__ x, const float* __restrict__ W1,
    const float* __restrict__ b1, const float* __restrict__ W2,
    const float* __restrict__ b2, float* __restrict__ fv) {
  __shared__ __align__(16) float xs[64 * 132];   // padded rows (33 float4)
  __shared__ __align__(16) float w2t[8 * 132];   // W2^T padded
  const int t = threadIdx.x;
  const int base = blockIdx.x * 64;

  // stage x tile (coalesced float4), pad rows to 132 floats
  const float4* xg = (const float4*)x;
  const size_t gbase = (size_t)base * 32;  // in float4 units
  const size_t xlim = (size_t)NNODES * 32;
#pragma unroll
  for (int r = 0; r < 8; ++r) {
    int e = t + r * 256;           // 0..2047
    int row = e >> 5, c4 = e & 31;
    size_t gi = gbase + e;
    float4 v = (gi < xlim) ? xg[gi] : make_float4(0.f, 0.f, 0.f, 0.f);
    ((float4*)xs)[row * 33 + c4] = v;
  }
  for (int i = t; i < 1024; i += 256) {
    int f = i >> 7, k = i & 127;
    w2t[f * 132 + k] = W2[k * 8 + f];
  }
  __syncthreads();

  const int j0 = (t & 31) * 4;
  const int i0 = (t >> 5) * 8;
  float acc[8][4];
#pragma unroll
  for (int i = 0; i < 8; ++i)
#pragma unroll
    for (int c = 0; c < 4; ++c) acc[i][c] = 0.f;

  for (int k4 = 0; k4 < 32; ++k4) {
    const int k = k4 * 4;
    float w[4][4];
#pragma unroll
    for (int r = 0; r < 4; ++r)
      *(float4*)w[r] = *(const float4*)&W1[(k + r) * NHID + j0];
#pragma unroll
    for (int i = 0; i < 8; ++i) {
      float xk[4];
      *(float4*)xk = *(const float4*)&xs[(i0 + i) * 132 + k];
#pragma unroll
      for (int c = 0; c < 4; ++c)
#pragma unroll
        for (int r = 0; r < 4; ++r)
          acc[i][c] = fmaf(xk[r], w[r][c], acc[i][c]);
    }
  }
  float bb[4];
  *(float4*)bb = *(const float4*)&b1[j0];
  __syncthreads();  // xs consumed; reuse as h tile
#pragma unroll
  for (int i = 0; i < 8; ++i) {
    float hv[4];
#pragma unroll
    for (int c = 0; c < 4; ++c) hv[c] = fmaxf(acc[i][c] + bb[c], 0.f);
    *(float4*)&xs[(i0 + i) * 132 + j0] = *(float4*)hv;
  }
  __syncthreads();

  // GEMM2: 64 nodes x 8 filts = 512 outputs, 2 per thread
#pragma unroll
  for (int rep = 0; rep < 2; ++rep) {
    int idx = t + rep * 256;
    int i = idx >> 3, f = idx & 7;
    float a = b2[f];
    for (int k = 0; k < NHID; k += 4) {
      float hvv[4], wvv[4];
      *(float4*)hvv = *(const float4*)&xs[i * 132 + k];
      *(float4*)wvv = *(const float4*)&w2t[f * 132 + k];
#pragma unroll
      for (int r = 0; r < 4; ++r) a = fmaf(hvv[r], wvv[r], a);
    }
    if (base + i < NNODES) fv[(size_t)(base + i) * NFILT + f] = a;
  }
}

// ---- Kernel: cnt[g] via binary search on sorted batch ----
__global__ void k_bounds(const int* __restrict__ batch, int* __restrict__ cnt) {
  int g = blockIdx.x * 64 + threadIdx.x;
  if (g >= NGRAPHS) return;
  int lo0 = 0, hi0 = NNODES;
  while (lo0 < hi0) { int mid = (lo0 + hi0) >> 1; if (batch[mid] < g) lo0 = mid + 1; else hi0 = mid; }
  int lo1 = lo0, hi1 = NNODES;
  while (lo1 < hi1) { int mid = (lo1 + hi1) >> 1; if (batch[mid] < g + 1) lo1 = mid + 1; else hi1 = mid; }
  cnt[g] = lo1 - lo0;
}

// ------- Kernel 2: pairs + y = relu(x16@W0+b0); segsum1 w/ run-length flush -------
// block 256 = 4 waves, each wave 32 contiguous nodes (lane j = out dim).
__global__ __launch_bounds__(256) void k_pairs(
    const float* __restrict__ fv, const int* __restrict__ edge_index,
    const int* __restrict__ didx, const int* __restrict__ batch,
    const float* __restrict__ W0, const float* __restrict__ b0,
    float* __restrict__ y, float* __restrict__ sums1) {
  __shared__ float w0s[16 * 64];
  __shared__ float b0s[64];
  const int t = threadIdx.x;
  for (int i = t; i < 1024; i += 256) w0s[i] = W0[i];
  if (t < 64) b0s[t] = b0[t];
  __syncthreads();

  const int wv = t >> 6, j = t & 63;
  const int n0 = blockIdx.x * 128 + wv * 32;

  int de = 0, gg = -1, uu = 0, vvx = 0;
  if (j < 32) {
    int nn = n0 + j;
    if (nn < NNODES) { de = didx[nn]; gg = batch[nn]; }
  }
  if (j < 32 && gg >= 0) { uu = edge_index[de]; vvx = edge_index[NEDGES + de]; }

  const float bb = b0s[j];
  float acc = 0.f;
  int cur_g = -1;

#pragma unroll 4
  for (int i = 0; i < 32; ++i) {
    int g = __shfl(gg, i);
    if (g >= 0) {
      int u = __shfl(uu, i);
      int v = __shfl(vvx, i);
      int n = n0 + i;
      float nb[8], ub[8], vb[8];
      *(float4*)&nb[0] = *(const float4*)&fv[(size_t)n * 8];
      *(float4*)&nb[4] = *(const float4*)&fv[(size_t)n * 8 + 4];
      *(float4*)&ub[0] = *(const float4*)&fv[(size_t)u * 8];
      *(float4*)&ub[4] = *(const float4*)&fv[(size_t)u * 8 + 4];
      *(float4*)&vb[0] = *(const float4*)&fv[(size_t)v * 8];
      *(float4*)&vb[4] = *(const float4*)&fv[(size_t)v * 8 + 4];
      float a = bb;
#pragma unroll
      for (int f = 0; f < 8; ++f) {
        a = fmaf(nb[f], w0s[(2 * f) * 64 + j], a);
        a = fmaf(fmaxf(ub[f], vb[f]), w0s[(2 * f + 1) * 64 + j], a);
      }
      a = fmaxf(a, 0.f);
      y[(size_t)n * 64 + j] = a;
      if (g != cur_g) {
        if (cur_g >= 0) atomicAdd(&sums1[cur_g * 64 + j], acc);
        acc = 0.f;
        cur_g = g;
      }
      acc += a;
    }
  }
  if (cur_g >= 0) atomicAdd(&sums1[cur_g * 64 + j], acc);
}

// ---------- Kernel 3/5: xm = (sums/max(cnt,1)) @ LW  (D = 64 or 128) ----------
template <int D>
__global__ void k_meanlin(const float* __restrict__ sums,
                          const int* __restrict__ cnt,
                          const float* __restrict__ LW,
                          float* __restrict__ xm) {
  __shared__ float m[64];
  const int g = blockIdx.x, t = threadIdx.x;
  const float c = fmaxf((float)cnt[g], 1.f);
  if (t < 64) m[t] = sums[g * 64 + t] / c;
  __syncthreads();
  float a = 0.f;
#pragma unroll
  for (int k = 0; k < 64; ++k) a = fmaf(m[k], LW[k * D + t], a);
  xm[g * D + t] = a;
}

// ---- Kernel 4: y = relu(y@g1W+g1b-xm1[g]) in-place; segsum2 w/ flush ----
__global__ __launch_bounds__(256) void k_ds1(
    float* __restrict__ y, const int* __restrict__ batch,
    const float* __restrict__ g1W, const float* __restrict__ g1b,
    const float* __restrict__ xm1, float* __restrict__ sums2) {
  __shared__ float gs[64 * 64];
  const int t = threadIdx.x;
  for (int i = t; i < 4096; i += 256) gs[i] = g1W[i];
  __syncthreads();
  const int wv = t >> 6, j = t & 63;
  const int n0 = blockIdx.x * 128 + wv * 32;

  int gg = -1;
  if (j < 32) {
    int nn = n0 + j;
    if (nn < NNODES) gg = batch[nn];
  }
  const float bb = g1b[j];
  float acc = 0.f, xmj = 0.f;
  int cur_g = -1;

#pragma unroll 2
  for (int i = 0; i < 32; ++i) {
    int g = __shfl(gg, i);
    if (g >= 0) {
      if (g != cur_g) {
        if (cur_g >= 0) atomicAdd(&sums2[cur_g * 64 + j], acc);
        acc = 0.f;
        cur_g = g;
        xmj = xm1[g * 64 + j];
      }
      const int n = n0 + i;
      const float yo = y[(size_t)n * 64 + j];
      float a = bb - xmj;
#pragma unroll
      for (int k = 0; k < 64; ++k)
        a = fmaf(__shfl(yo, k), gs[k * 64 + j], a);
      a = fmaxf(a, 0.f);
      y[(size_t)n * 64 + j] = a;
      acc += a;
    }
  }
  if (cur_g >= 0) atomicAdd(&sums2[cur_g * 64 + j], acc);
}

// ---- Kernel 6: h = relu(z@g2W+g2b-xm2[g]) -> d_out; BN partials per block ----
// block 128 threads (f = t), 128 nodes/block in chunks of 4.
__global__ __launch_bounds__(128) void k_ds2(
    const float* __restrict__ z, const int* __restrict__ batch,
    const float* __restrict__ g2W, const float* __restrict__ g2b,
    const float* __restrict__ xm2, float* __restrict__ h,
    float* __restrict__ pmu, float* __restrict__ psq) {
  __shared__ float gs[64 * 128];  // 32 KB
  const int f = threadIdx.x;
  for (int i = f; i < 8192; i += 128) gs[i] = g2W[i];
  __syncthreads();
  const int nbase = blockIdx.x * 128;
  const float bb = g2b[f];
  float s = 0.f, q = 0.f;
  for (int c = 0; c < 32; ++c) {
    const int nn = nbase + c * 4;
    if (nn >= NNODES) break;  // NNODES%4==0: chunks are full or absent
    float a0 = bb, a1 = bb, a2 = bb, a3 = bb;
    const float4* z0 = (const float4*)&z[(size_t)(nn + 0) * 64];
    const float4* z1 = (const float4*)&z[(size_t)(nn + 1) * 64];
    const float4* z2 = (const float4*)&z[(size_t)(nn + 2) * 64];
    const float4* z3 = (const float4*)&z[(size_t)(nn + 3) * 64];
#pragma unroll
    for (int k4 = 0; k4 < 16; ++k4) {
      float zv0[4], zv1[4], zv2[4], zv3[4], w[4];
      *(float4*)zv0 = z0[k4];
      *(float4*)zv1 = z1[k4];
      *(float4*)zv2 = z2[k4];
      *(float4*)zv3 = z3[k4];
#pragma unroll
      for (int r = 0; r < 4; ++r) w[r] = gs[(k4 * 4 + r) * 128 + f];
#pragma unroll
      for (int r = 0; r < 4; ++r) {
        a0 = fmaf(zv0[r], w[r], a0);
        a1 = fmaf(zv1[r], w[r], a1);
        a2 = fmaf(zv2[r], w[r], a2);
        a3 = fmaf(zv3[r], w[r], a3);
      }
    }
    int g0 = batch[nn], g1 = batch[nn + 1], g2 = batch[nn + 2], g3 = batch[nn + 3];
    a0 = fmaxf(a0 - xm2[g0 * 128 + f], 0.f);
    a1 = fmaxf(a1 - xm2[g1 * 128 + f], 0.f);
    a2 = fmaxf(a2 - xm2[g2 * 128 + f], 0.f);
    a3 = fmaxf(a3 - xm2[g3 * 128 + f], 0.f);
    h[(size_t)(nn + 0) * 128 + f] = a0;
    h[(size_t)(nn + 1) * 128 + f] = a1;
    h[(size_t)(nn + 2) * 128 + f] = a2;
    h[(size_t)(nn + 3) * 128 + f] = a3;
    s += a0 + a1 + a2 + a3;
    q = fmaf(a0, a0, q); q = fmaf(a1, a1, q);
    q = fmaf(a2, a2, q); q = fmaf(a3, a3, q);
  }
  pmu[blockIdx.x * 128 + f] = s;
  psq[blockIdx.x * 128 + f] = q;
}

// ---- Kernel: reduce BN partials ----
__global__ void k_red(const float* __restrict__ pmu, const float* __restrict__ psq,
                      float* __restrict__ musum, float* __restrict__ sqsum) {
  const int f = threadIdx.x & 127;
  const bool mu = threadIdx.x < 128;
  const float* src = mu ? pmu : psq;
  float s = 0.f;
  for (int b = blockIdx.x; b < NBLK2; b += 32) s += src[b * 128 + f];
  atomicAdd(mu ? &musum[f] : &sqsum[f], s);
}

// ------- Kernel 7: out = x + (h-mu)*rsqrt(var+eps)*gamma + beta (in-place) -------
__global__ __launch_bounds__(256) void k_bn(
    const float* __restrict__ x, float* hout,
    const float* __restrict__ musum, const float* __restrict__ sqsum,
    const float* __restrict__ gamma, const float* __restrict__ beta) {
  const size_t i = (size_t)blockIdx.x * 256 + threadIdx.x;  // float4 index
  const int f0 = (int)(i & 31) * 4;
  const float invN = 1.f / (float)NNODES;
  float mu[4], sc[4], be[4];
#pragma unroll
  for (int r = 0; r < 4; ++r) {
    float m = musum[f0 + r] * invN;
    float v = sqsum[f0 + r] * invN - m * m;
    sc[r] = rsqrtf(v + BN_EPS) * gamma[f0 + r];
    mu[r] = m;
    be[r] = beta[f0 + r];
  }
  float4 hv = ((const float4*)hout)[i];
  float4 xv = ((const float4*)x)[i];
  float4 o;
  o.x = xv.x + (hv.x - mu[0]) * sc[0] + be[0];
  o.y = xv.y + (hv.y - mu[1]) * sc[1] + be[1];
  o.z = xv.z + (hv.z - mu[2]) * sc[2] + be[2];
  o.w = xv.w + (hv.w - mu[3]) * sc[3] + be[3];
  ((float4*)hout)[i] = o;
}

extern "C" void kernel_launch(void* const* d_in, const int* in_sizes, int n_in,
                              void* d_out, int out_size, void* d_ws,
                              size_t ws_size, hipStream_t stream) {
  const float* x     = (const float*)d_in[0];
  const float* W1    = (const float*)d_in[1];
  const float* b1    = (const float*)d_in[2];
  const float* W2    = (const float*)d_in[3];
  const float* b2    = (const float*)d_in[4];
  const float* W0    = (const float*)d_in[5];
  const float* b0    = (const float*)d_in[6];
  const float* g1W   = (const float*)d_in[7];
  const float* g1b   = (const float*)d_in[8];
  const float* l1W   = (const float*)d_in[9];
  const float* g2W   = (const float*)d_in[10];
  const float* g2b   = (const float*)d_in[11];
  const float* l2W   = (const float*)d_in[12];
  const float* gamma = (const float*)d_in[13];
  const float* beta  = (const float*)d_in[14];
  const int* edge_index = (const int*)d_in[15];
  const int* batch      = (const int*)d_in[16];
  const int* didx       = (const int*)d_in[17];
  float* out = (float*)d_out;

  char* ws = (char*)d_ws;
  float* fv    = (float*)(ws + 0);            // N*8*4 = 16,000,000 B
  float* pmu   = (float*)(ws + 0);            // 2,000,384 B (reuses fv after k_pairs)
  float* psq   = (float*)(ws + 2000384);      // 2,000,384 B
  float* y     = (float*)(ws + 16000000);     // 128,000,000 B
  float* sums1 = (float*)(ws + 144000000);    // 131,072 B
  float* sums2 = (float*)(ws + 144131072);    // 131,072 B
  float* musum = (float*)(ws + 144262144);    // 512 B
  float* sqsum = (float*)(ws + 144262656);    // 512 B
  int*   cnt   = (int*)  (ws + 144263168);    // 2,048 B
  float* xm1   = (float*)(ws + 144265216);    // 131,072 B
  float* xm2   = (float*)(ws + 144396288);    // 262,144 B
  // total 144,658,432 B

  hipMemsetAsync(ws + 144000000, 0, 263168, stream);  // sums1,sums2,musum,sqsum

  k_bounds<<<8, 64, 0, stream>>>(batch, cnt);
  k_filt<<<(NNODES + 63) / 64, 256, 0, stream>>>(x, W1, b1, W2, b2, fv);
  k_pairs<<<NBLK2, 256, 0, stream>>>(fv, edge_index, didx, batch, W0, b0, y, sums1);
  k_meanlin<64><<<NGRAPHS, 64, 0, stream>>>(sums1, cnt, l1W, xm1);
  k_ds1<<<NBLK2, 256, 0, stream>>>(y, batch, g1W, g1b, xm1, sums2);
  k_meanlin<128><<<NGRAPHS, 128, 0, stream>>>(sums2, cnt, l2W, xm2);
  k_ds2<<<NBLK2, 128, 0, stream>>>(y, batch, g2W, g2b, xm2, out, pmu, psq);
  k_red<<<32, 256, 0, stream>>>(pmu, psq, musum, sqsum);
  k_bn<<<(NNODES * 128 / 4) / 256, 256, 0, stream>>>(x, out, musum, sqsum,
                                                     gamma, beta);
}

// Round 4
// 1294.739 us; speedup vs baseline: 2.4439x; 1.1303x over previous
//
#include <hip/hip_runtime.h>
#include <hip/hip_bf16.h>

#define NNODES 500000
#define NEDGES 8000000
#define NGRAPHS 512
#define NFEAT 128
#define NHID 128
#define NFILT 8
#define ODIM 64
#define BN_EPS 1e-5f
#define NBLK2 3907  // ceil(NNODES/128)

// ---------------- Kernel 1: fv = relu(x@W1+b1)@W2 + b2  [N,8] ----------------
__global__ __launch_bounds__(256) void k_filt(
    const float* __restrict__ x, const float* __restrict__ W1,
    const float* __restrict__ b1, const float* __restrict__ W2,
    const float* __restrict__ b2, float* __restrict__ fv) {
  __shared__ __align__(16) float xs[64 * 132];   // padded rows (33 float4)
  __shared__ __align__(16) float w2t[8 * 132];   // W2^T padded
  const int t = threadIdx.x;
  const int base = blockIdx.x * 64;

  const float4* xg = (const float4*)x;
  const size_t gbase = (size_t)base * 32;
  const size_t xlim = (size_t)NNODES * 32;
#pragma unroll
  for (int r = 0; r < 8; ++r) {
    int e = t + r * 256;
    int row = e >> 5, c4 = e & 31;
    size_t gi = gbase + e;
    float4 v = (gi < xlim) ? xg[gi] : make_float4(0.f, 0.f, 0.f, 0.f);
    ((float4*)xs)[row * 33 + c4] = v;
  }
  for (int i = t; i < 1024; i += 256) {
    int f = i >> 7, k = i & 127;
    w2t[f * 132 + k] = W2[k * 8 + f];
  }
  __syncthreads();

  const int j0 = (t & 31) * 4;
  const int i0 = (t >> 5) * 8;
  float acc[8][4];
#pragma unroll
  for (int i = 0; i < 8; ++i)
#pragma unroll
    for (int c = 0; c < 4; ++c) acc[i][c] = 0.f;

  for (int k4 = 0; k4 < 32; ++k4) {
    const int k = k4 * 4;
    float w[4][4];
#pragma unroll
    for (int r = 0; r < 4; ++r)
      *(float4*)w[r] = *(const float4*)&W1[(k + r) * NHID + j0];
#pragma unroll
    for (int i = 0; i < 8; ++i) {
      float xk[4];
      *(float4*)xk = *(const float4*)&xs[(i0 + i) * 132 + k];
#pragma unroll
      for (int c = 0; c < 4; ++c)
#pragma unroll
        for (int r = 0; r < 4; ++r)
          acc[i][c] = fmaf(xk[r], w[r][c], acc[i][c]);
    }
  }
  float bb[4];
  *(float4*)bb = *(const float4*)&b1[j0];
  __syncthreads();
#pragma unroll
  for (int i = 0; i < 8; ++i) {
    float hv[4];
#pragma unroll
    for (int c = 0; c < 4; ++c) hv[c] = fmaxf(acc[i][c] + bb[c], 0.f);
    *(float4*)&xs[(i0 + i) * 132 + j0] = *(float4*)hv;
  }
  __syncthreads();

#pragma unroll
  for (int rep = 0; rep < 2; ++rep) {
    int idx = t + rep * 256;
    int i = idx >> 3, f = idx & 7;
    float a = b2[f];
    for (int k = 0; k < NHID; k += 4) {
      float hvv[4], wvv[4];
      *(float4*)hvv = *(const float4*)&xs[i * 132 + k];
      *(float4*)wvv = *(const float4*)&w2t[f * 132 + k];
#pragma unroll
      for (int r = 0; r < 4; ++r) a = fmaf(hvv[r], wvv[r], a);
    }
    if (base + i < NNODES) fv[(size_t)(base + i) * NFILT + f] = a;
  }
}

// ---- cnt[g] via binary search on sorted batch ----
__global__ void k_bounds(const int* __restrict__ batch, int* __restrict__ cnt) {
  int g = blockIdx.x * 64 + threadIdx.x;
  if (g >= NGRAPHS) return;
  int lo0 = 0, hi0 = NNODES;
  while (lo0 < hi0) { int mid = (lo0 + hi0) >> 1; if (batch[mid] < g) lo0 = mid + 1; else hi0 = mid; }
  int lo1 = lo0, hi1 = NNODES;
  while (lo1 < hi1) { int mid = (lo1 + hi1) >> 1; if (batch[mid] < g + 1) lo1 = mid + 1; else hi1 = mid; }
  cnt[g] = lo1 - lo0;
}

// ------- Kernel 2: pairs + y = relu(x16@W0+b0); segsum1 run-length flush -------
__global__ __launch_bounds__(256) void k_pairs(
    const float* __restrict__ fv, const int* __restrict__ edge_index,
    const int* __restrict__ didx, const int* __restrict__ batch,
    const float* __restrict__ W0, const float* __restrict__ b0,
    float* __restrict__ y, float* __restrict__ sums1) {
  __shared__ float w0s[16 * 64];
  __shared__ float b0s[64];
  const int t = threadIdx.x;
  for (int i = t; i < 1024; i += 256) w0s[i] = W0[i];
  if (t < 64) b0s[t] = b0[t];
  __syncthreads();

  const int wv = t >> 6, j = t & 63;
  const int n0 = blockIdx.x * 128 + wv * 32;

  int de = 0, gg = -1, uu = 0, vvx = 0;
  if (j < 32) {
    int nn = n0 + j;
    if (nn < NNODES) { de = didx[nn]; gg = batch[nn]; }
  }
  if (j < 32 && gg >= 0) { uu = edge_index[de]; vvx = edge_index[NEDGES + de]; }

  const float bb = b0s[j];
  float acc = 0.f;
  int cur_g = -1;

#pragma unroll 4
  for (int i = 0; i < 32; ++i) {
    int g = __shfl(gg, i);
    if (g >= 0) {
      int u = __shfl(uu, i);
      int v = __shfl(vvx, i);
      int n = n0 + i;
      float nb[8], ub[8], vb[8];
      *(float4*)&nb[0] = *(const float4*)&fv[(size_t)n * 8];
      *(float4*)&nb[4] = *(const float4*)&fv[(size_t)n * 8 + 4];
      *(float4*)&ub[0] = *(const float4*)&fv[(size_t)u * 8];
      *(float4*)&ub[4] = *(const float4*)&fv[(size_t)u * 8 + 4];
      *(float4*)&vb[0] = *(const float4*)&fv[(size_t)v * 8];
      *(float4*)&vb[4] = *(const float4*)&fv[(size_t)v * 8 + 4];
      float a = bb;
#pragma unroll
      for (int f = 0; f < 8; ++f) {
        a = fmaf(nb[f], w0s[(2 * f) * 64 + j], a);
        a = fmaf(fmaxf(ub[f], vb[f]), w0s[(2 * f + 1) * 64 + j], a);
      }
      a = fmaxf(a, 0.f);
      y[(size_t)n * 64 + j] = a;
      if (g != cur_g) {
        if (cur_g >= 0) atomicAdd(&sums1[cur_g * 64 + j], acc);
        acc = 0.f;
        cur_g = g;
      }
      acc += a;
    }
  }
  if (cur_g >= 0) atomicAdd(&sums1[cur_g * 64 + j], acc);
}

// ---------- xm = (sums/max(cnt,1)) @ LW  (D = 64 or 128) ----------
template <int D>
__global__ void k_meanlin(const float* __restrict__ sums,
                          const int* __restrict__ cnt,
                          const float* __restrict__ LW,
                          float* __restrict__ xm) {
  __shared__ float m[64];
  const int g = blockIdx.x, t = threadIdx.x;
  const float c = fmaxf((float)cnt[g], 1.f);
  if (t < 64) m[t] = sums[g * 64 + t] / c;
  __syncthreads();
  float a = 0.f;
#pragma unroll
  for (int k = 0; k < 64; ++k) a = fmaf(m[k], LW[k * D + t], a);
  xm[g * D + t] = a;
}

// ---- Kernel 4: y = relu(y@g1W+g1b-xm1[g]) in-place; segsum2 w/ flush ----
// 4 waves/block, wave owns 32 contiguous rows (wave-private in-place: safe).
__global__ __launch_bounds__(256) void k_ds1(
    float* y, const int* __restrict__ batch,
    const float* __restrict__ g1W, const float* __restrict__ g1b,
    const float* __restrict__ xm1, float* __restrict__ sums2) {
  __shared__ float gs[64 * 64];  // 16 KB
  const int t = threadIdx.x;
  for (int i = t; i < 4096; i += 256) gs[i] = g1W[i];
  __syncthreads();
  const int wv = t >> 6, j = t & 63;
  const int n0 = blockIdx.x * 128 + wv * 32;
  if (n0 >= NNODES) return;  // whole-wave exit (NNODES % 32 == 0)

  const float bb = g1b[j];
  float acc = 0.f, xmj = 0.f;
  int cur_g = -1;

  for (int c = 0; c < 8; ++c) {
    const int nn = n0 + c * 4;
    float a[4] = {bb, bb, bb, bb};
    const float4* z0 = (const float4*)&y[(size_t)(nn + 0) * 64];
    const float4* z1 = (const float4*)&y[(size_t)(nn + 1) * 64];
    const float4* z2 = (const float4*)&y[(size_t)(nn + 2) * 64];
    const float4* z3 = (const float4*)&y[(size_t)(nn + 3) * 64];
#pragma unroll
    for (int k4 = 0; k4 < 16; ++k4) {
      float zv0[4], zv1[4], zv2[4], zv3[4], w[4];
      *(float4*)zv0 = z0[k4];
      *(float4*)zv1 = z1[k4];
      *(float4*)zv2 = z2[k4];
      *(float4*)zv3 = z3[k4];
#pragma unroll
      for (int r = 0; r < 4; ++r) w[r] = gs[(k4 * 4 + r) * 64 + j];
#pragma unroll
      for (int r = 0; r < 4; ++r) {
        a[0] = fmaf(zv0[r], w[r], a[0]);
        a[1] = fmaf(zv1[r], w[r], a[1]);
        a[2] = fmaf(zv2[r], w[r], a[2]);
        a[3] = fmaf(zv3[r], w[r], a[3]);
      }
    }
#pragma unroll
    for (int r = 0; r < 4; ++r) {
      const int g = batch[nn + r];
      if (g != cur_g) {
        if (cur_g >= 0) atomicAdd(&sums2[cur_g * 64 + j], acc);
        acc = 0.f;
        cur_g = g;
        xmj = xm1[g * 64 + j];
      }
      float av = fmaxf(a[r] - xmj, 0.f);
      y[(size_t)(nn + r) * 64 + j] = av;
      acc += av;
    }
  }
  if (cur_g >= 0) atomicAdd(&sums2[cur_g * 64 + j], acc);
}

// ---- Kernel 6: h = relu(z@g2W+g2b-xm2[g]) -> bf16 IN-PLACE over z ----
// WAVE-PRIVATE rows this time: 4 waves/block, wave owns 32 rows; lane j
// computes columns 2j,2j+1 (packed bf16x2 store). No cross-wave hazard.
__global__ __launch_bounds__(256) void k_ds2(
    const float* z, const int* __restrict__ batch,
    const float* __restrict__ g2W, const float* __restrict__ g2b,
    const float* __restrict__ xm2, __hip_bfloat16* h,
    float* __restrict__ pmu, float* __restrict__ psq) {
  __shared__ float gs[64 * 128];          // 32 KB
  __shared__ float ps[4][128], pq[4][128]; // 4 KB
  const int t = threadIdx.x;
  for (int i = t; i < 8192; i += 256) gs[i] = g2W[i];
  __syncthreads();
  const int wv = t >> 6, j = t & 63;
  const int c0 = 2 * j, c1 = 2 * j + 1;
  const int n0 = blockIdx.x * 128 + wv * 32;

  float s0 = 0.f, s1 = 0.f, q0 = 0.f, q1 = 0.f;
  if (n0 < NNODES) {
    const float bb0 = g2b[c0], bb1 = g2b[c1];
    for (int c = 0; c < 8; ++c) {
      const int nn = n0 + c * 4;
      float a0[2] = {bb0, bb1}, a1[2] = {bb0, bb1};
      float a2[2] = {bb0, bb1}, a3[2] = {bb0, bb1};
      const float4* z0 = (const float4*)&z[(size_t)(nn + 0) * 64];
      const float4* z1 = (const float4*)&z[(size_t)(nn + 1) * 64];
      const float4* z2 = (const float4*)&z[(size_t)(nn + 2) * 64];
      const float4* z3 = (const float4*)&z[(size_t)(nn + 3) * 64];
#pragma unroll
      for (int k4 = 0; k4 < 16; ++k4) {
        float zv0[4], zv1[4], zv2[4], zv3[4];
        *(float4*)zv0 = z0[k4];
        *(float4*)zv1 = z1[k4];
        *(float4*)zv2 = z2[k4];
        *(float4*)zv3 = z3[k4];
#pragma unroll
        for (int r = 0; r < 4; ++r) {
          float2 w = *(const float2*)&gs[(k4 * 4 + r) * 128 + c0];
          a0[0] = fmaf(zv0[r], w.x, a0[0]); a0[1] = fmaf(zv0[r], w.y, a0[1]);
          a1[0] = fmaf(zv1[r], w.x, a1[0]); a1[1] = fmaf(zv1[r], w.y, a1[1]);
          a2[0] = fmaf(zv2[r], w.x, a2[0]); a2[1] = fmaf(zv2[r], w.y, a2[1]);
          a3[0] = fmaf(zv3[r], w.x, a3[0]); a3[1] = fmaf(zv3[r], w.y, a3[1]);
        }
      }
      float* aa[4] = {a0, a1, a2, a3};
#pragma unroll
      for (int r = 0; r < 4; ++r) {
        const int g = batch[nn + r];
        float v0 = fmaxf(aa[r][0] - xm2[g * 128 + c0], 0.f);
        float v1 = fmaxf(aa[r][1] - xm2[g * 128 + c1], 0.f);
        __hip_bfloat162 hv2;
        hv2.x = __float2bfloat16(v0);
        hv2.y = __float2bfloat16(v1);
        *(__hip_bfloat162*)&h[(size_t)(nn + r) * 128 + c0] = hv2;
        s0 += v0; q0 = fmaf(v0, v0, q0);
        s1 += v1; q1 = fmaf(v1, v1, q1);
      }
    }
  }
  ps[wv][c0] = s0; ps[wv][c1] = s1;
  pq[wv][c0] = q0; pq[wv][c1] = q1;
  __syncthreads();
  if (t < 128) {
    pmu[blockIdx.x * 128 + t] = ps[0][t] + ps[1][t] + ps[2][t] + ps[3][t];
    psq[blockIdx.x * 128 + t] = pq[0][t] + pq[1][t] + pq[2][t] + pq[3][t];
  }
}

// ---- reduce BN partials ----
__global__ void k_red(const float* __restrict__ pmu, const float* __restrict__ psq,
                      float* __restrict__ musum, float* __restrict__ sqsum) {
  const int f = threadIdx.x & 127;
  const bool mu = threadIdx.x < 128;
  const float* src = mu ? pmu : psq;
  float s = 0.f;
  for (int b = blockIdx.x; b < NBLK2; b += 32) s += src[b * 128 + f];
  atomicAdd(mu ? &musum[f] : &sqsum[f], s);
}

// ------- Kernel 7: out = x + (h-mu)*rsqrt(var+eps)*gamma + beta (h is bf16) -------
__global__ __launch_bounds__(256) void k_bn(
    const float* __restrict__ x, const __hip_bfloat16* __restrict__ h,
    float* __restrict__ out,
    const float* __restrict__ musum, const float* __restrict__ sqsum,
    const float* __restrict__ gamma, const float* __restrict__ beta) {
  const size_t i = (size_t)blockIdx.x * 256 + threadIdx.x;  // 4-feat group index
  const int f0 = (int)(i & 31) * 4;
  const float invN = 1.f / (float)NNODES;
  float mu[4], sc[4], be[4];
#pragma unroll
  for (int r = 0; r < 4; ++r) {
    float m = musum[f0 + r] * invN;
    float v = sqsum[f0 + r] * invN - m * m;
    sc[r] = rsqrtf(v + BN_EPS) * gamma[f0 + r];
    mu[r] = m;
    be[r] = beta[f0 + r];
  }
  uint2 hu = ((const uint2*)h)[i];  // 4 bf16
  float hv[4];
  hv[0] = __uint_as_float(hu.x << 16);
  hv[1] = __uint_as_float(hu.x & 0xffff0000u);
  hv[2] = __uint_as_float(hu.y << 16);
  hv[3] = __uint_as_float(hu.y & 0xffff0000u);
  float4 xv = ((const float4*)x)[i];
  float4 o;
  o.x = xv.x + (hv[0] - mu[0]) * sc[0] + be[0];
  o.y = xv.y + (hv[1] - mu[1]) * sc[1] + be[1];
  o.z = xv.z + (hv[2] - mu[2]) * sc[2] + be[2];
  o.w = xv.w + (hv[3] - mu[3]) * sc[3] + be[3];
  ((float4*)out)[i] = o;
}

extern "C" void kernel_launch(void* const* d_in, const int* in_sizes, int n_in,
                              void* d_out, int out_size, void* d_ws,
                              size_t ws_size, hipStream_t stream) {
  const float* x     = (const float*)d_in[0];
  const float* W1    = (const float*)d_in[1];
  const float* b1    = (const float*)d_in[2];
  const float* W2    = (const float*)d_in[3];
  const float* b2    = (const float*)d_in[4];
  const float* W0    = (const float*)d_in[5];
  const float* b0    = (const float*)d_in[6];
  const float* g1W   = (const float*)d_in[7];
  const float* g1b   = (const float*)d_in[8];
  const float* l1W   = (const float*)d_in[9];
  const float* g2W   = (const float*)d_in[10];
  const float* g2b   = (const float*)d_in[11];
  const float* l2W   = (const float*)d_in[12];
  const float* gamma = (const float*)d_in[13];
  const float* beta  = (const float*)d_in[14];
  const int* edge_index = (const int*)d_in[15];
  const int* batch      = (const int*)d_in[16];
  const int* didx       = (const int*)d_in[17];
  float* out = (float*)d_out;

  char* ws = (char*)d_ws;
  float* fv    = (float*)(ws + 0);            // 16,000,000 B
  float* pmu   = (float*)(ws + 0);            // reuses fv after k_pairs
  float* psq   = (float*)(ws + 2000384);
  float* y     = (float*)(ws + 16000000);     // 128,000,000 B (z f32, then h bf16 in-place)
  float* sums1 = (float*)(ws + 144000000);
  float* sums2 = (float*)(ws + 144131072);
  float* musum = (float*)(ws + 144262144);
  float* sqsum = (float*)(ws + 144262656);
  int*   cnt   = (int*)  (ws + 144263168);
  float* xm1   = (float*)(ws + 144265216);
  float* xm2   = (float*)(ws + 144396288);
  __hip_bfloat16* hbf = (__hip_bfloat16*)y;   // in-place over y

  hipMemsetAsync(ws + 144000000, 0, 263168, stream);

  k_bounds<<<8, 64, 0, stream>>>(batch, cnt);
  k_filt<<<(NNODES + 63) / 64, 256, 0, stream>>>(x, W1, b1, W2, b2, fv);
  k_pairs<<<NBLK2, 256, 0, stream>>>(fv, edge_index, didx, batch, W0, b0, y, sums1);
  k_meanlin<64><<<NGRAPHS, 64, 0, stream>>>(sums1, cnt, l1W, xm1);
  k_ds1<<<NBLK2, 256, 0, stream>>>(y, batch, g1W, g1b, xm1, sums2);
  k_meanlin<128><<<NGRAPHS, 128, 0, stream>>>(sums2, cnt, l2W, xm2);
  k_ds2<<<NBLK2, 256, 0, stream>>>(y, batch, g2W, g2b, xm2, hbf, pmu, psq);
  k_red<<<32, 256, 0, stream>>>(pmu, psq, musum, sqsum);
  k_bn<<<(NNODES * 128 / 4) / 256, 256, 0, stream>>>(x, hbf, out, musum, sqsum,
                                                     gamma, beta);
}

// Round 5
// 768.190 us; speedup vs baseline: 4.1191x; 1.6854x over previous
//
#include <hip/hip_runtime.h>
#include <hip/hip_bf16.h>

#define NNODES 500000
#define NEDGES 8000000
#define NGRAPHS 512
#define NFEAT 128
#define NHID 128
#define NFILT 8
#define ODIM 64
#define BN_EPS 1e-5f
#define NBLK2 3907  // ceil(NNODES/128)

typedef __attribute__((ext_vector_type(8))) short bf16x8;
typedef __attribute__((ext_vector_type(4))) float f32x4;
#define MFMA16(a, b, c) __builtin_amdgcn_mfma_f32_16x16x32_bf16(a, b, c, 0, 0, 0)

__device__ inline ushort f2bs(float f) {
  union { __hip_bfloat16 h; ushort u; } cv;
  cv.h = __float2bfloat16(f);
  return cv.u;
}

// ---------------- Kernel 1: fv = relu(x@W1+b1)@W2 + b2  [N,8] f32 ----------------
__global__ __launch_bounds__(256) void k_filt(
    const float* __restrict__ x, const float* __restrict__ W1,
    const float* __restrict__ b1, const float* __restrict__ W2,
    const float* __restrict__ b2, float* __restrict__ fv) {
  __shared__ __align__(16) float xs[64 * 132];
  __shared__ __align__(16) float w2t[8 * 132];
  const int t = threadIdx.x;
  const int base = blockIdx.x * 64;

  const float4* xg = (const float4*)x;
  const size_t gbase = (size_t)base * 32;
  const size_t xlim = (size_t)NNODES * 32;
#pragma unroll
  for (int r = 0; r < 8; ++r) {
    int e = t + r * 256;
    int row = e >> 5, c4 = e & 31;
    size_t gi = gbase + e;
    float4 v = (gi < xlim) ? xg[gi] : make_float4(0.f, 0.f, 0.f, 0.f);
    ((float4*)xs)[row * 33 + c4] = v;
  }
  for (int i = t; i < 1024; i += 256) {
    int f = i >> 7, k = i & 127;
    w2t[f * 132 + k] = W2[k * 8 + f];
  }
  __syncthreads();

  const int j0 = (t & 31) * 4;
  const int i0 = (t >> 5) * 8;
  float acc[8][4];
#pragma unroll
  for (int i = 0; i < 8; ++i)
#pragma unroll
    for (int c = 0; c < 4; ++c) acc[i][c] = 0.f;

  for (int k4 = 0; k4 < 32; ++k4) {
    const int k = k4 * 4;
    float w[4][4];
#pragma unroll
    for (int r = 0; r < 4; ++r)
      *(float4*)w[r] = *(const float4*)&W1[(k + r) * NHID + j0];
#pragma unroll
    for (int i = 0; i < 8; ++i) {
      float xk[4];
      *(float4*)xk = *(const float4*)&xs[(i0 + i) * 132 + k];
#pragma unroll
      for (int c = 0; c < 4; ++c)
#pragma unroll
        for (int r = 0; r < 4; ++r)
          acc[i][c] = fmaf(xk[r], w[r][c], acc[i][c]);
    }
  }
  float bb[4];
  *(float4*)bb = *(const float4*)&b1[j0];
  __syncthreads();
#pragma unroll
  for (int i = 0; i < 8; ++i) {
    float hv[4];
#pragma unroll
    for (int c = 0; c < 4; ++c) hv[c] = fmaxf(acc[i][c] + bb[c], 0.f);
    *(float4*)&xs[(i0 + i) * 132 + j0] = *(float4*)hv;
  }
  __syncthreads();

#pragma unroll
  for (int rep = 0; rep < 2; ++rep) {
    int idx = t + rep * 256;
    int i = idx >> 3, f = idx & 7;
    float a = b2[f];
    for (int k = 0; k < NHID; k += 4) {
      float hvv[4], wvv[4];
      *(float4*)hvv = *(const float4*)&xs[i * 132 + k];
      *(float4*)wvv = *(const float4*)&w2t[f * 132 + k];
#pragma unroll
      for (int r = 0; r < 4; ++r) a = fmaf(hvv[r], wvv[r], a);
    }
    if (base + i < NNODES) fv[(size_t)(base + i) * NFILT + f] = a;
  }
}

// ---- cnt[g] via binary search on sorted batch ----
__global__ void k_bounds(const int* __restrict__ batch, int* __restrict__ cnt) {
  int g = blockIdx.x * 64 + threadIdx.x;
  if (g >= NGRAPHS) return;
  int lo0 = 0, hi0 = NNODES;
  while (lo0 < hi0) { int mid = (lo0 + hi0) >> 1; if (batch[mid] < g) lo0 = mid + 1; else hi0 = mid; }
  int lo1 = lo0, hi1 = NNODES;
  while (lo1 < hi1) { int mid = (lo1 + hi1) >> 1; if (batch[mid] < g + 1) lo1 = mid + 1; else hi1 = mid; }
  cnt[g] = lo1 - lo0;
}

// ---- pack g1W/g2W into MFMA A-fragment layout (swapped-op: A[m=c][k]=W[k][c]) ----
__global__ void k_pack(const float* __restrict__ g1W, const float* __restrict__ g2W,
                       ushort* __restrict__ pW1, ushort* __restrict__ pW2) {
  int idx = blockIdx.x * 256 + threadIdx.x;
  if (idx < 4096) {
    int j = idx & 7, l = (idx >> 3) & 63, kb = (idx >> 9) & 1, ncb = idx >> 10;
    int k = kb * 32 + (l >> 4) * 8 + j, c = ncb * 16 + (l & 15);
    pW1[idx] = f2bs(g1W[k * 64 + c]);
  }
  if (idx < 8192) {
    int j = idx & 7, l = (idx >> 3) & 63, kb = (idx >> 9) & 1, ncb = idx >> 10;
    int k = kb * 32 + (l >> 4) * 8 + j, c = ncb * 16 + (l & 15);
    pW2[idx] = f2bs(g2W[k * 128 + c]);
  }
}

// ------- Kernel 2: pairs + y = relu(x16@W0+b0) -> bf16; segsum1 run-length -------
__global__ __launch_bounds__(256) void k_pairs(
    const float* __restrict__ fv, const int* __restrict__ edge_index,
    const int* __restrict__ didx, const int* __restrict__ batch,
    const float* __restrict__ W0, const float* __restrict__ b0,
    ushort* __restrict__ y, float* __restrict__ sums1) {
  __shared__ float w0s[16 * 64];
  __shared__ float b0s[64];
  const int t = threadIdx.x;
  for (int i = t; i < 1024; i += 256) w0s[i] = W0[i];
  if (t < 64) b0s[t] = b0[t];
  __syncthreads();

  const int wv = t >> 6, j = t & 63;
  const int n0 = blockIdx.x * 128 + wv * 32;

  int de = 0, gg = -1, uu = 0, vvx = 0;
  if (j < 32) {
    int nn = n0 + j;
    if (nn < NNODES) { de = didx[nn]; gg = batch[nn]; }
  }
  if (j < 32 && gg >= 0) { uu = edge_index[de]; vvx = edge_index[NEDGES + de]; }

  const float bb = b0s[j];
  float acc = 0.f;
  int cur_g = -1;

#pragma unroll 4
  for (int i = 0; i < 32; ++i) {
    int g = __shfl(gg, i);
    if (g >= 0) {
      int u = __shfl(uu, i);
      int v = __shfl(vvx, i);
      int n = n0 + i;
      float nb[8], ub[8], vb[8];
      *(float4*)&nb[0] = *(const float4*)&fv[(size_t)n * 8];
      *(float4*)&nb[4] = *(const float4*)&fv[(size_t)n * 8 + 4];
      *(float4*)&ub[0] = *(const float4*)&fv[(size_t)u * 8];
      *(float4*)&ub[4] = *(const float4*)&fv[(size_t)u * 8 + 4];
      *(float4*)&vb[0] = *(const float4*)&fv[(size_t)v * 8];
      *(float4*)&vb[4] = *(const float4*)&fv[(size_t)v * 8 + 4];
      float a = bb;
#pragma unroll
      for (int f = 0; f < 8; ++f) {
        a = fmaf(nb[f], w0s[(2 * f) * 64 + j], a);
        a = fmaf(fmaxf(ub[f], vb[f]), w0s[(2 * f + 1) * 64 + j], a);
      }
      a = fmaxf(a, 0.f);
      y[(size_t)n * 64 + j] = f2bs(a);
      if (g != cur_g) {
        if (cur_g >= 0) atomicAdd(&sums1[cur_g * 64 + j], acc);
        acc = 0.f;
        cur_g = g;
      }
      acc += a;
    }
  }
  if (cur_g >= 0) atomicAdd(&sums1[cur_g * 64 + j], acc);
}

// ---------- xm = (sums/max(cnt,1)) @ LW  (D = 64 or 128) ----------
template <int D>
__global__ void k_meanlin(const float* __restrict__ sums,
                          const int* __restrict__ cnt,
                          const float* __restrict__ LW,
                          float* __restrict__ xm) {
  __shared__ float m[64];
  const int g = blockIdx.x, t = threadIdx.x;
  const float c = fmaxf((float)cnt[g], 1.f);
  if (t < 64) m[t] = sums[g * 64 + t] / c;
  __syncthreads();
  float a = 0.f;
#pragma unroll
  for (int k = 0; k < 64; ++k) a = fmaf(m[k], LW[k * D + t], a);
  xm[g * D + t] = a;
}

// ---- Kernel 4 (MFMA): y2 = relu(y@g1W + g1b - xm1[g]) bf16; segsum2 ----
// 4 waves/block, wave = 32 nodes. Swapped-op: D[c][n] = (g1W^T)(y^T).
__global__ __launch_bounds__(256) void k_ds1(
    const ushort* __restrict__ ybf, const int* __restrict__ batch,
    const ushort* __restrict__ pW1, const float* __restrict__ g1b,
    const float* __restrict__ xm1, ushort* __restrict__ y2,
    float* __restrict__ sums2) {
  const int t = threadIdx.x, wv = t >> 6, l = t & 63;
  const int n0 = blockIdx.x * 128 + wv * 32;
  if (n0 >= NNODES) return;
  const int lr = l & 15, lg = l >> 4;
  const int c0 = lg * 4;

  union { uint4 u; bf16x8 b; } bf[2][2];
#pragma unroll
  for (int mt = 0; mt < 2; ++mt)
#pragma unroll
    for (int kb = 0; kb < 2; ++kb)
      bf[mt][kb].u = *(const uint4*)&ybf[(size_t)(n0 + mt * 16 + lr) * 64 + kb * 32 + lg * 8];

  union { uint4 u; bf16x8 b; } af[4][2];
#pragma unroll
  for (int ncb = 0; ncb < 4; ++ncb)
#pragma unroll
    for (int kb = 0; kb < 2; ++kb)
      af[ncb][kb].u = *(const uint4*)&pW1[((ncb * 2 + kb) * 64 + l) * 8];

  f32x4 acc[2][4];
#pragma unroll
  for (int mt = 0; mt < 2; ++mt)
#pragma unroll
    for (int ncb = 0; ncb < 4; ++ncb) {
      acc[mt][ncb] = (f32x4){0.f, 0.f, 0.f, 0.f};
      acc[mt][ncb] = MFMA16(af[ncb][0].b, bf[mt][0].b, acc[mt][ncb]);
      acc[mt][ncb] = MFMA16(af[ncb][1].b, bf[mt][1].b, acc[mt][ncb]);
    }

  const int g0 = batch[n0 + lr], g1 = batch[n0 + 16 + lr];
  const int gfirst = __shfl(g0, 0);
  const bool uni = __all(g0 == gfirst) && __all(g1 == gfirst);

  float wsum[4][4];
#pragma unroll
  for (int ncb = 0; ncb < 4; ++ncb)
#pragma unroll
    for (int r = 0; r < 4; ++r) wsum[ncb][r] = 0.f;

#pragma unroll
  for (int mt = 0; mt < 2; ++mt) {
    const int n = n0 + mt * 16 + lr;
    const int g = mt ? g1 : g0;
#pragma unroll
    for (int ncb = 0; ncb < 4; ++ncb) {
      const int c = ncb * 16 + c0;
      float xmv[4], bbv[4];
      *(float4*)xmv = *(const float4*)&xm1[g * 64 + c];
      *(float4*)bbv = *(const float4*)&g1b[c];
      ushort st[4];
#pragma unroll
      for (int r = 0; r < 4; ++r) {
        float v = fmaxf(acc[mt][ncb][r] + bbv[r] - xmv[r], 0.f);
        st[r] = f2bs(v);
        if (uni) wsum[ncb][r] += v;
        else atomicAdd(&sums2[g * 64 + c + r], v);
      }
      *(ushort4*)&y2[(size_t)n * 64 + c] = *(ushort4*)st;
    }
  }
  if (uni) {
#pragma unroll
    for (int ncb = 0; ncb < 4; ++ncb)
#pragma unroll
      for (int r = 0; r < 4; ++r) {
        float w = wsum[ncb][r];
        w += __shfl_xor(w, 1); w += __shfl_xor(w, 2);
        w += __shfl_xor(w, 4); w += __shfl_xor(w, 8);
        if (lr == 0) atomicAdd(&sums2[gfirst * 64 + ncb * 16 + c0 + r], w);
      }
  }
}

// ---- Kernel 6a (MFMA, stats only): v = relu(y2@g2W + g2b - xm2[g]); BN partials ----
__global__ __launch_bounds__(256) void k_ds2a(
    const ushort* __restrict__ y2, const int* __restrict__ batch,
    const ushort* __restrict__ pW2, const float* __restrict__ g2b,
    const float* __restrict__ xm2,
    float* __restrict__ pmu, float* __restrict__ psq) {
  __shared__ float ps[4][128], pq[4][128];
  const int t = threadIdx.x, wv = t >> 6, l = t & 63;
  const int lr = l & 15, lg = l >> 4, c0 = lg * 4;
  const int n0r = blockIdx.x * 128 + wv * 32;
  const bool act = n0r < NNODES;
  const int n0 = act ? n0r : 0;

  union { uint4 u; bf16x8 b; } bf[2][2];
#pragma unroll
  for (int mt = 0; mt < 2; ++mt)
#pragma unroll
    for (int kb = 0; kb < 2; ++kb)
      bf[mt][kb].u = *(const uint4*)&y2[(size_t)(n0 + mt * 16 + lr) * 64 + kb * 32 + lg * 8];

  const int g0 = batch[n0 + lr], g1 = batch[n0 + 16 + lr];

#pragma unroll
  for (int ncb = 0; ncb < 8; ++ncb) {
    union { uint4 u; bf16x8 b; } af0, af1;
    af0.u = *(const uint4*)&pW2[((ncb * 2 + 0) * 64 + l) * 8];
    af1.u = *(const uint4*)&pW2[((ncb * 2 + 1) * 64 + l) * 8];
    f32x4 a0 = (f32x4){0.f, 0.f, 0.f, 0.f}, a1 = (f32x4){0.f, 0.f, 0.f, 0.f};
    a0 = MFMA16(af0.b, bf[0][0].b, a0); a0 = MFMA16(af1.b, bf[0][1].b, a0);
    a1 = MFMA16(af0.b, bf[1][0].b, a1); a1 = MFMA16(af1.b, bf[1][1].b, a1);

    const int c = ncb * 16 + c0;
    float xm0[4], xm1v[4], bbv[4];
    *(float4*)xm0 = *(const float4*)&xm2[g0 * 128 + c];
    *(float4*)xm1v = *(const float4*)&xm2[g1 * 128 + c];
    *(float4*)bbv = *(const float4*)&g2b[c];
    float w[4], q[4];
#pragma unroll
    for (int r = 0; r < 4; ++r) {
      float v0 = fmaxf(a0[r] + bbv[r] - xm0[r], 0.f);
      float v1 = fmaxf(a1[r] + bbv[r] - xm1v[r], 0.f);
      if (!act) { v0 = 0.f; v1 = 0.f; }
      w[r] = v0 + v1;
      q[r] = fmaf(v0, v0, v1 * v1);
    }
#pragma unroll
    for (int r = 0; r < 4; ++r) {
      float wr = w[r], qr = q[r];
      wr += __shfl_xor(wr, 1); wr += __shfl_xor(wr, 2);
      wr += __shfl_xor(wr, 4); wr += __shfl_xor(wr, 8);
      qr += __shfl_xor(qr, 1); qr += __shfl_xor(qr, 2);
      qr += __shfl_xor(qr, 4); qr += __shfl_xor(qr, 8);
      if (lr == 0) { ps[wv][c + r] = wr; pq[wv][c + r] = qr; }
    }
  }
  __syncthreads();
  if (t < 128) {
    pmu[(size_t)blockIdx.x * 128 + t] = ps[0][t] + ps[1][t] + ps[2][t] + ps[3][t];
    psq[(size_t)blockIdx.x * 128 + t] = pq[0][t] + pq[1][t] + pq[2][t] + pq[3][t];
  }
}

// ---- reduce BN partials ----
__global__ void k_red(const float* __restrict__ pmu, const float* __restrict__ psq,
                      float* __restrict__ musum, float* __restrict__ sqsum) {
  const int f = threadIdx.x & 127;
  const bool mu = threadIdx.x < 128;
  const float* src = mu ? pmu : psq;
  float s = 0.f;
  for (int b = blockIdx.x; b < NBLK2; b += 32) s += src[(size_t)b * 128 + f];
  atomicAdd(mu ? &musum[f] : &sqsum[f], s);
}

// ---- Kernel 7 (MFMA fused): recompute h, out = x + (h-mu)*sc + beta ----
__global__ __launch_bounds__(256) void k_bn(
    const ushort* __restrict__ y2, const int* __restrict__ batch,
    const ushort* __restrict__ pW2, const float* __restrict__ g2b,
    const float* __restrict__ xm2, const float* __restrict__ x,
    const float* __restrict__ musum, const float* __restrict__ sqsum,
    const float* __restrict__ gamma, const float* __restrict__ beta,
    float* __restrict__ out) {
  __shared__ float smu[128], ssc[128], sbe[128];
  const int t = threadIdx.x, wv = t >> 6, l = t & 63;
  const int lr = l & 15, lg = l >> 4, c0 = lg * 4;
  if (t < 128) {
    const float invN = 1.f / (float)NNODES;
    float m = musum[t] * invN;
    float v = sqsum[t] * invN - m * m;
    smu[t] = m;
    ssc[t] = rsqrtf(v + BN_EPS) * gamma[t];
    sbe[t] = beta[t];
  }
  __syncthreads();
  const int n0 = blockIdx.x * 128 + wv * 32;
  if (n0 >= NNODES) return;

  union { uint4 u; bf16x8 b; } bf[2][2];
#pragma unroll
  for (int mt = 0; mt < 2; ++mt)
#pragma unroll
    for (int kb = 0; kb < 2; ++kb)
      bf[mt][kb].u = *(const uint4*)&y2[(size_t)(n0 + mt * 16 + lr) * 64 + kb * 32 + lg * 8];

  const int g0 = batch[n0 + lr], g1 = batch[n0 + 16 + lr];

#pragma unroll
  for (int ncb = 0; ncb < 8; ++ncb) {
    union { uint4 u; bf16x8 b; } af0, af1;
    af0.u = *(const uint4*)&pW2[((ncb * 2 + 0) * 64 + l) * 8];
    af1.u = *(const uint4*)&pW2[((ncb * 2 + 1) * 64 + l) * 8];
    f32x4 a0 = (f32x4){0.f, 0.f, 0.f, 0.f}, a1 = (f32x4){0.f, 0.f, 0.f, 0.f};
    a0 = MFMA16(af0.b, bf[0][0].b, a0); a0 = MFMA16(af1.b, bf[0][1].b, a0);
    a1 = MFMA16(af0.b, bf[1][0].b, a1); a1 = MFMA16(af1.b, bf[1][1].b, a1);

    const int c = ncb * 16 + c0;
    float bbv[4], muv[4], scv[4], bev[4];
    *(float4*)bbv = *(const float4*)&g2b[c];
    *(float4*)muv = *(const float4*)&smu[c];
    *(float4*)scv = *(const float4*)&ssc[c];
    *(float4*)bev = *(const float4*)&sbe[c];
#pragma unroll
    for (int mt = 0; mt < 2; ++mt) {
      const int n = n0 + mt * 16 + lr;
      const int g = mt ? g1 : g0;
      float xmv[4], xv[4], o[4];
      *(float4*)xmv = *(const float4*)&xm2[g * 128 + c];
      *(float4*)xv = *(const float4*)&x[(size_t)n * 128 + c];
      const f32x4& aa = mt ? a1 : a0;
#pragma unroll
      for (int r = 0; r < 4; ++r) {
        float v = fmaxf(aa[r] + bbv[r] - xmv[r], 0.f);
        o[r] = xv[r] + (v - muv[r]) * scv[r] + bev[r];
      }
      *(float4*)&out[(size_t)n * 128 + c] = *(float4*)o;
    }
  }
}

extern "C" void kernel_launch(void* const* d_in, const int* in_sizes, int n_in,
                              void* d_out, int out_size, void* d_ws,
                              size_t ws_size, hipStream_t stream) {
  const float* x     = (const float*)d_in[0];
  const float* W1    = (const float*)d_in[1];
  const float* b1    = (const float*)d_in[2];
  const float* W2    = (const float*)d_in[3];
  const float* b2    = (const float*)d_in[4];
  const float* W0    = (const float*)d_in[5];
  const float* b0    = (const float*)d_in[6];
  const float* g1W   = (const float*)d_in[7];
  const float* g1b   = (const float*)d_in[8];
  const float* l1W   = (const float*)d_in[9];
  const float* g2W   = (const float*)d_in[10];
  const float* g2b   = (const float*)d_in[11];
  const float* l2W   = (const float*)d_in[12];
  const float* gamma = (const float*)d_in[13];
  const float* beta  = (const float*)d_in[14];
  const int* edge_index = (const int*)d_in[15];
  const int* batch      = (const int*)d_in[16];
  const int* didx       = (const int*)d_in[17];
  float* out = (float*)d_out;

  char* ws = (char*)d_ws;
  float*  fv    = (float*) (ws + 0);           // 16,000,000 B (dead after k_pairs)
  float*  pmu   = (float*) (ws + 0);           // 2,000,384 B (reuses fv)
  float*  psq   = (float*) (ws + 2000384);     // 2,000,384 B
  ushort* ybf   = (ushort*)(ws + 16000000);    // N*64*2 = 64,000,000 B
  ushort* y2    = (ushort*)(ws + 80000000);    // N*64*2 = 64,000,000 B
  float*  sums1 = (float*) (ws + 144000000);   // 131,072 B
  float*  sums2 = (float*) (ws + 144131072);   // 131,072 B
  float*  musum = (float*) (ws + 144262144);   // 512 B
  float*  sqsum = (float*) (ws + 144262656);   // 512 B
  int*    cnt   = (int*)   (ws + 144263168);   // 2,048 B
  float*  xm1   = (float*) (ws + 144265216);   // 131,072 B
  float*  xm2   = (float*) (ws + 144396288);   // 262,144 B
  ushort* pW1   = (ushort*)(ws + 144658432);   // 8,192 B
  ushort* pW2   = (ushort*)(ws + 144666624);   // 16,384 B  (end 144,683,008)

  hipMemsetAsync(ws + 144000000, 0, 263168, stream);  // sums1,sums2,musum,sqsum

  k_bounds<<<8, 64, 0, stream>>>(batch, cnt);
  k_pack<<<32, 256, 0, stream>>>(g1W, g2W, pW1, pW2);
  k_filt<<<(NNODES + 63) / 64, 256, 0, stream>>>(x, W1, b1, W2, b2, fv);
  k_pairs<<<NBLK2, 256, 0, stream>>>(fv, edge_index, didx, batch, W0, b0, ybf, sums1);
  k_meanlin<64><<<NGRAPHS, 64, 0, stream>>>(sums1, cnt, l1W, xm1);
  k_ds1<<<NBLK2, 256, 0, stream>>>(ybf, batch, pW1, g1b, xm1, y2, sums2);
  k_meanlin<128><<<NGRAPHS, 128, 0, stream>>>(sums2, cnt, l2W, xm2);
  k_ds2a<<<NBLK2, 256, 0, stream>>>(y2, batch, pW2, g2b, xm2, pmu, psq);
  k_red<<<32, 256, 0, stream>>>(pmu, psq, musum, sqsum);
  k_bn<<<NBLK2, 256, 0, stream>>>(y2, batch, pW2, g2b, xm2, x, musum, sqsum,
                                  gamma, beta, out);
}

// Round 6
// 624.007 us; speedup vs baseline: 5.0708x; 1.2311x over previous
//
#include <hip/hip_runtime.h>
#include <hip/hip_bf16.h>

#define NNODES 500000
#define NEDGES 8000000
#define NGRAPHS 512
#define NFEAT 128
#define NHID 128
#define NFILT 8
#define ODIM 64
#define BN_EPS 1e-5f
#define NBLK2 3907  // ceil(NNODES/128)

typedef __attribute__((ext_vector_type(8))) short bf16x8;
typedef __attribute__((ext_vector_type(4))) float f32x4;
#define MFMA16(a, b, c) __builtin_amdgcn_mfma_f32_16x16x32_bf16(a, b, c, 0, 0, 0)

__device__ inline ushort f2bs(float f) {
  union { __hip_bfloat16 h; ushort u; } cv;
  cv.h = __float2bfloat16(f);
  return cv.u;
}

// ---- pack W1/g1W/g2W into MFMA A-fragment layout (swapped-op: A[m=c][k]=W[k][c]) ----
__global__ void k_pack(const float* __restrict__ g1W, const float* __restrict__ g2W,
                       const float* __restrict__ W1,
                       ushort* __restrict__ pW1, ushort* __restrict__ pW2,
                       ushort* __restrict__ pW0) {
  int idx = blockIdx.x * 256 + threadIdx.x;
  if (idx < 4096) {
    int j = idx & 7, l = (idx >> 3) & 63, kb = (idx >> 9) & 1, ncb = idx >> 10;
    int k = kb * 32 + (l >> 4) * 8 + j, c = ncb * 16 + (l & 15);
    pW1[idx] = f2bs(g1W[k * 64 + c]);
  }
  if (idx < 8192) {
    int j = idx & 7, l = (idx >> 3) & 63, kb = (idx >> 9) & 1, ncb = idx >> 10;
    int k = kb * 32 + (l >> 4) * 8 + j, c = ncb * 16 + (l & 15);
    pW2[idx] = f2bs(g2W[k * 128 + c]);
  }
  if (idx < 16384) {
    int j = idx & 7, l = (idx >> 3) & 63, kb = (idx >> 9) & 3, ncb = idx >> 11;
    int k = kb * 32 + (l >> 4) * 8 + j, c = ncb * 16 + (l & 15);
    pW0[idx] = f2bs(W1[k * 128 + c]);
  }
}

// ---- Kernel 1 (MFMA): fv = relu(x@W1+b1)@W2 + b2  [N,8] f32 ----
// 4 waves/block, wave = 32 nodes. GEMM1 swapped-op MFMA; GEMM2 in-register
// partial dot + shfl_xor reduce over lane-groups.
__global__ __launch_bounds__(256) void k_filt(
    const float* __restrict__ x, const ushort* __restrict__ pW0,
    const float* __restrict__ b1, const float* __restrict__ W2,
    const float* __restrict__ b2, float* __restrict__ fv) {
  __shared__ float w2s[128 * 12];  // W2 rows padded to 12 (bank-spread, float4-aligned)
  const int t = threadIdx.x;
  for (int i = t; i < 1024; i += 256) {
    int c = i >> 3, f = i & 7;
    w2s[c * 12 + f] = W2[i];
  }
  __syncthreads();
  const int wv = t >> 6, l = t & 63;
  const int lr = l & 15, lg = l >> 4;
  const int n0 = blockIdx.x * 128 + wv * 32;
  if (n0 >= NNODES) return;  // wave-private from here on (no barriers)

  // B-fragments: x rows, f32 -> bf16 in registers
  union { uint4 u; bf16x8 b; } bf[2][4];
#pragma unroll
  for (int mt = 0; mt < 2; ++mt)
#pragma unroll
    for (int kb = 0; kb < 4; ++kb) {
      const float* src = &x[(size_t)(n0 + mt * 16 + lr) * 128 + kb * 32 + lg * 8];
      float v[8];
      *(float4*)&v[0] = *(const float4*)src;
      *(float4*)&v[4] = *(const float4*)(src + 4);
      ushort s[8];
#pragma unroll
      for (int e = 0; e < 8; ++e) s[e] = f2bs(v[e]);
      bf[mt][kb].u = *(uint4*)s;
    }

  float pf0[8], pf1[8];
#pragma unroll
  for (int f = 0; f < 8; ++f) { pf0[f] = 0.f; pf1[f] = 0.f; }

#pragma unroll
  for (int ncb = 0; ncb < 8; ++ncb) {
    union { uint4 u; bf16x8 b; } af[4];
#pragma unroll
    for (int kb = 0; kb < 4; ++kb)
      af[kb].u = *(const uint4*)&pW0[((ncb * 4 + kb) * 64 + l) * 8];
    f32x4 a0 = (f32x4){0.f, 0.f, 0.f, 0.f};
    f32x4 a1 = (f32x4){0.f, 0.f, 0.f, 0.f};
#pragma unroll
    for (int kb = 0; kb < 4; ++kb) {
      a0 = MFMA16(af[kb].b, bf[0][kb].b, a0);
      a1 = MFMA16(af[kb].b, bf[1][kb].b, a1);
    }
    float bbv[4];
    *(float4*)bbv = *(const float4*)&b1[ncb * 16 + lg * 4];
#pragma unroll
    for (int r = 0; r < 4; ++r) {
      const int c = ncb * 16 + lg * 4 + r;
      float h0 = fmaxf(a0[r] + bbv[r], 0.f);
      float h1 = fmaxf(a1[r] + bbv[r], 0.f);
      float w20[4], w21[4];
      *(float4*)w20 = *(const float4*)&w2s[c * 12];
      *(float4*)w21 = *(const float4*)&w2s[c * 12 + 4];
#pragma unroll
      for (int f = 0; f < 4; ++f) {
        pf0[f]     = fmaf(h0, w20[f], pf0[f]);
        pf0[f + 4] = fmaf(h0, w21[f], pf0[f + 4]);
        pf1[f]     = fmaf(h1, w20[f], pf1[f]);
        pf1[f + 4] = fmaf(h1, w21[f], pf1[f + 4]);
      }
    }
  }
  // reduce partials across lg (lane bits 4,5)
#pragma unroll
  for (int f = 0; f < 8; ++f) {
    pf0[f] += __shfl_xor(pf0[f], 16); pf0[f] += __shfl_xor(pf0[f], 32);
    pf1[f] += __shfl_xor(pf1[f], 16); pf1[f] += __shfl_xor(pf1[f], 32);
  }
  if (lg == 0) {
    float o0[8], o1[8];
#pragma unroll
    for (int f = 0; f < 8; ++f) {
      float bb = b2[f];
      o0[f] = pf0[f] + bb;
      o1[f] = pf1[f] + bb;
    }
    *(float4*)&fv[(size_t)(n0 + lr) * 8]          = *(float4*)&o0[0];
    *(float4*)&fv[(size_t)(n0 + lr) * 8 + 4]      = *(float4*)&o0[4];
    *(float4*)&fv[(size_t)(n0 + 16 + lr) * 8]     = *(float4*)&o1[0];
    *(float4*)&fv[(size_t)(n0 + 16 + lr) * 8 + 4] = *(float4*)&o1[4];
  }
}

// ---- cnt[g] via binary search on sorted batch ----
__global__ void k_bounds(const int* __restrict__ batch, int* __restrict__ cnt) {
  int g = blockIdx.x * 64 + threadIdx.x;
  if (g >= NGRAPHS) return;
  int lo0 = 0, hi0 = NNODES;
  while (lo0 < hi0) { int mid = (lo0 + hi0) >> 1; if (batch[mid] < g) lo0 = mid + 1; else hi0 = mid; }
  int lo1 = lo0, hi1 = NNODES;
  while (lo1 < hi1) { int mid = (lo1 + hi1) >> 1; if (batch[mid] < g + 1) lo1 = mid + 1; else hi1 = mid; }
  cnt[g] = lo1 - lo0;
}

// ------- Kernel 2: pairs + y = relu(x16@W0+b0) -> bf16; segsum1 run-length -------
__global__ __launch_bounds__(256) void k_pairs(
    const float* __restrict__ fv, const int* __restrict__ edge_index,
    const int* __restrict__ didx, const int* __restrict__ batch,
    const float* __restrict__ W0, const float* __restrict__ b0,
    ushort* __restrict__ y, float* __restrict__ sums1) {
  __shared__ float w0s[16 * 64];
  __shared__ float b0s[64];
  const int t = threadIdx.x;
  for (int i = t; i < 1024; i += 256) w0s[i] = W0[i];
  if (t < 64) b0s[t] = b0[t];
  __syncthreads();

  const int wv = t >> 6, j = t & 63;
  const int n0 = blockIdx.x * 128 + wv * 32;

  int de = 0, gg = -1, uu = 0, vvx = 0;
  if (j < 32) {
    int nn = n0 + j;
    if (nn < NNODES) { de = didx[nn]; gg = batch[nn]; }
  }
  if (j < 32 && gg >= 0) { uu = edge_index[de]; vvx = edge_index[NEDGES + de]; }

  const float bb = b0s[j];
  float acc = 0.f;
  int cur_g = -1;

#pragma unroll 4
  for (int i = 0; i < 32; ++i) {
    int g = __shfl(gg, i);
    if (g >= 0) {
      int u = __shfl(uu, i);
      int v = __shfl(vvx, i);
      int n = n0 + i;
      float nb[8], ub[8], vb[8];
      *(float4*)&nb[0] = *(const float4*)&fv[(size_t)n * 8];
      *(float4*)&nb[4] = *(const float4*)&fv[(size_t)n * 8 + 4];
      *(float4*)&ub[0] = *(const float4*)&fv[(size_t)u * 8];
      *(float4*)&ub[4] = *(const float4*)&fv[(size_t)u * 8 + 4];
      *(float4*)&vb[0] = *(const float4*)&fv[(size_t)v * 8];
      *(float4*)&vb[4] = *(const float4*)&fv[(size_t)v * 8 + 4];
      float a = bb;
#pragma unroll
      for (int f = 0; f < 8; ++f) {
        a = fmaf(nb[f], w0s[(2 * f) * 64 + j], a);
        a = fmaf(fmaxf(ub[f], vb[f]), w0s[(2 * f + 1) * 64 + j], a);
      }
      a = fmaxf(a, 0.f);
      y[(size_t)n * 64 + j] = f2bs(a);
      if (g != cur_g) {
        if (cur_g >= 0) atomicAdd(&sums1[cur_g * 64 + j], acc);
        acc = 0.f;
        cur_g = g;
      }
      acc += a;
    }
  }
  if (cur_g >= 0) atomicAdd(&sums1[cur_g * 64 + j], acc);
}

// ---------- xm = (sums/max(cnt,1)) @ LW  (D = 64 or 128) ----------
template <int D>
__global__ void k_meanlin(const float* __restrict__ sums,
                          const int* __restrict__ cnt,
                          const float* __restrict__ LW,
                          float* __restrict__ xm) {
  __shared__ float m[64];
  const int g = blockIdx.x, t = threadIdx.x;
  const float c = fmaxf((float)cnt[g], 1.f);
  if (t < 64) m[t] = sums[g * 64 + t] / c;
  __syncthreads();
  float a = 0.f;
#pragma unroll
  for (int k = 0; k < 64; ++k) a = fmaf(m[k], LW[k * D + t], a);
  xm[g * D + t] = a;
}

// ---- Kernel 4 (MFMA): y2 = relu(y@g1W + g1b - xm1[g]) bf16; segsum2 ----
__global__ __launch_bounds__(256) void k_ds1(
    const ushort* __restrict__ ybf, const int* __restrict__ batch,
    const ushort* __restrict__ pW1, const float* __restrict__ g1b,
    const float* __restrict__ xm1, ushort* __restrict__ y2,
    float* __restrict__ sums2) {
  const int t = threadIdx.x, wv = t >> 6, l = t & 63;
  const int n0 = blockIdx.x * 128 + wv * 32;
  if (n0 >= NNODES) return;
  const int lr = l & 15, lg = l >> 4;
  const int c0 = lg * 4;

  union { uint4 u; bf16x8 b; } bf[2][2];
#pragma unroll
  for (int mt = 0; mt < 2; ++mt)
#pragma unroll
    for (int kb = 0; kb < 2; ++kb)
      bf[mt][kb].u = *(const uint4*)&ybf[(size_t)(n0 + mt * 16 + lr) * 64 + kb * 32 + lg * 8];

  union { uint4 u; bf16x8 b; } af[4][2];
#pragma unroll
  for (int ncb = 0; ncb < 4; ++ncb)
#pragma unroll
    for (int kb = 0; kb < 2; ++kb)
      af[ncb][kb].u = *(const uint4*)&pW1[((ncb * 2 + kb) * 64 + l) * 8];

  f32x4 acc[2][4];
#pragma unroll
  for (int mt = 0; mt < 2; ++mt)
#pragma unroll
    for (int ncb = 0; ncb < 4; ++ncb) {
      acc[mt][ncb] = (f32x4){0.f, 0.f, 0.f, 0.f};
      acc[mt][ncb] = MFMA16(af[ncb][0].b, bf[mt][0].b, acc[mt][ncb]);
      acc[mt][ncb] = MFMA16(af[ncb][1].b, bf[mt][1].b, acc[mt][ncb]);
    }

  const int g0 = batch[n0 + lr], g1 = batch[n0 + 16 + lr];
  const int gfirst = __shfl(g0, 0);
  const bool uni = __all(g0 == gfirst) && __all(g1 == gfirst);

  float wsum[4][4];
#pragma unroll
  for (int ncb = 0; ncb < 4; ++ncb)
#pragma unroll
    for (int r = 0; r < 4; ++r) wsum[ncb][r] = 0.f;

#pragma unroll
  for (int mt = 0; mt < 2; ++mt) {
    const int n = n0 + mt * 16 + lr;
    const int g = mt ? g1 : g0;
#pragma unroll
    for (int ncb = 0; ncb < 4; ++ncb) {
      const int c = ncb * 16 + c0;
      float xmv[4], bbv[4];
      *(float4*)xmv = *(const float4*)&xm1[g * 64 + c];
      *(float4*)bbv = *(const float4*)&g1b[c];
      ushort st[4];
#pragma unroll
      for (int r = 0; r < 4; ++r) {
        float v = fmaxf(acc[mt][ncb][r] + bbv[r] - xmv[r], 0.f);
        st[r] = f2bs(v);
        if (uni) wsum[ncb][r] += v;
        else atomicAdd(&sums2[g * 64 + c + r], v);
      }
      *(ushort4*)&y2[(size_t)n * 64 + c] = *(ushort4*)st;
    }
  }
  if (uni) {
#pragma unroll
    for (int ncb = 0; ncb < 4; ++ncb)
#pragma unroll
      for (int r = 0; r < 4; ++r) {
        float w = wsum[ncb][r];
        w += __shfl_xor(w, 1); w += __shfl_xor(w, 2);
        w += __shfl_xor(w, 4); w += __shfl_xor(w, 8);
        if (lr == 0) atomicAdd(&sums2[gfirst * 64 + ncb * 16 + c0 + r], w);
      }
  }
}

// ---- Kernel 6a (MFMA, stats only): v = relu(y2@g2W + g2b - xm2[g]); BN partials ----
__global__ __launch_bounds__(256) void k_ds2a(
    const ushort* __restrict__ y2, const int* __restrict__ batch,
    const ushort* __restrict__ pW2, const float* __restrict__ g2b,
    const float* __restrict__ xm2,
    float* __restrict__ pmu, float* __restrict__ psq) {
  __shared__ float ps[4][128], pq[4][128];
  const int t = threadIdx.x, wv = t >> 6, l = t & 63;
  const int lr = l & 15, lg = l >> 4, c0 = lg * 4;
  const int n0r = blockIdx.x * 128 + wv * 32;
  const bool act = n0r < NNODES;
  const int n0 = act ? n0r : 0;

  union { uint4 u; bf16x8 b; } bf[2][2];
#pragma unroll
  for (int mt = 0; mt < 2; ++mt)
#pragma unroll
    for (int kb = 0; kb < 2; ++kb)
      bf[mt][kb].u = *(const uint4*)&y2[(size_t)(n0 + mt * 16 + lr) * 64 + kb * 32 + lg * 8];

  const int g0 = batch[n0 + lr], g1 = batch[n0 + 16 + lr];

#pragma unroll
  for (int ncb = 0; ncb < 8; ++ncb) {
    union { uint4 u; bf16x8 b; } af0, af1;
    af0.u = *(const uint4*)&pW2[((ncb * 2 + 0) * 64 + l) * 8];
    af1.u = *(const uint4*)&pW2[((ncb * 2 + 1) * 64 + l) * 8];
    f32x4 a0 = (f32x4){0.f, 0.f, 0.f, 0.f}, a1 = (f32x4){0.f, 0.f, 0.f, 0.f};
    a0 = MFMA16(af0.b, bf[0][0].b, a0); a0 = MFMA16(af1.b, bf[0][1].b, a0);
    a1 = MFMA16(af0.b, bf[1][0].b, a1); a1 = MFMA16(af1.b, bf[1][1].b, a1);

    const int c = ncb * 16 + c0;
    float xm0[4], xm1v[4], bbv[4];
    *(float4*)xm0 = *(const float4*)&xm2[g0 * 128 + c];
    *(float4*)xm1v = *(const float4*)&xm2[g1 * 128 + c];
    *(float4*)bbv = *(const float4*)&g2b[c];
    float w[4], q[4];
#pragma unroll
    for (int r = 0; r < 4; ++r) {
      float v0 = fmaxf(a0[r] + bbv[r] - xm0[r], 0.f);
      float v1 = fmaxf(a1[r] + bbv[r] - xm1v[r], 0.f);
      if (!act) { v0 = 0.f; v1 = 0.f; }
      w[r] = v0 + v1;
      q[r] = fmaf(v0, v0, v1 * v1);
    }
#pragma unroll
    for (int r = 0; r < 4; ++r) {
      float wr = w[r], qr = q[r];
      wr += __shfl_xor(wr, 1); wr += __shfl_xor(wr, 2);
      wr += __shfl_xor(wr, 4); wr += __shfl_xor(wr, 8);
      qr += __shfl_xor(qr, 1); qr += __shfl_xor(qr, 2);
      qr += __shfl_xor(qr, 4); qr += __shfl_xor(qr, 8);
      if (lr == 0) { ps[wv][c + r] = wr; pq[wv][c + r] = qr; }
    }
  }
  __syncthreads();
  if (t < 128) {
    pmu[(size_t)blockIdx.x * 128 + t] = ps[0][t] + ps[1][t] + ps[2][t] + ps[3][t];
    psq[(size_t)blockIdx.x * 128 + t] = pq[0][t] + pq[1][t] + pq[2][t] + pq[3][t];
  }
}

// ---- reduce BN partials ----
__global__ void k_red(const float* __restrict__ pmu, const float* __restrict__ psq,
                      float* __restrict__ musum, float* __restrict__ sqsum) {
  const int f = threadIdx.x & 127;
  const bool mu = threadIdx.x < 128;
  const float* src = mu ? pmu : psq;
  float s = 0.f;
  for (int b = blockIdx.x; b < NBLK2; b += 32) s += src[(size_t)b * 128 + f];
  atomicAdd(mu ? &musum[f] : &sqsum[f], s);
}

// ---- Kernel 7 (MFMA fused): recompute h, out = x + (h-mu)*sc + beta ----
__global__ __launch_bounds__(256) void k_bn(
    const ushort* __restrict__ y2, const int* __restrict__ batch,
    const ushort* __restrict__ pW2, const float* __restrict__ g2b,
    const float* __restrict__ xm2, const float* __restrict__ x,
    const float* __restrict__ musum, const float* __restrict__ sqsum,
    const float* __restrict__ gamma, const float* __restrict__ beta,
    float* __restrict__ out) {
  __shared__ float smu[128], ssc[128], sbe[128];
  const int t = threadIdx.x, wv = t >> 6, l = t & 63;
  const int lr = l & 15, lg = l >> 4, c0 = lg * 4;
  if (t < 128) {
    const float invN = 1.f / (float)NNODES;
    float m = musum[t] * invN;
    float v = sqsum[t] * invN - m * m;
    smu[t] = m;
    ssc[t] = rsqrtf(v + BN_EPS) * gamma[t];
    sbe[t] = beta[t];
  }
  __syncthreads();
  const int n0 = blockIdx.x * 128 + wv * 32;
  if (n0 >= NNODES) return;

  union { uint4 u; bf16x8 b; } bf[2][2];
#pragma unroll
  for (int mt = 0; mt < 2; ++mt)
#pragma unroll
    for (int kb = 0; kb < 2; ++kb)
      bf[mt][kb].u = *(const uint4*)&y2[(size_t)(n0 + mt * 16 + lr) * 64 + kb * 32 + lg * 8];

  const int g0 = batch[n0 + lr], g1 = batch[n0 + 16 + lr];

#pragma unroll
  for (int ncb = 0; ncb < 8; ++ncb) {
    union { uint4 u; bf16x8 b; } af0, af1;
    af0.u = *(const uint4*)&pW2[((ncb * 2 + 0) * 64 + l) * 8];
    af1.u = *(const uint4*)&pW2[((ncb * 2 + 1) * 64 + l) * 8];
    f32x4 a0 = (f32x4){0.f, 0.f, 0.f, 0.f}, a1 = (f32x4){0.f, 0.f, 0.f, 0.f};
    a0 = MFMA16(af0.b, bf[0][0].b, a0); a0 = MFMA16(af1.b, bf[0][1].b, a0);
    a1 = MFMA16(af0.b, bf[1][0].b, a1); a1 = MFMA16(af1.b, bf[1][1].b, a1);

    const int c = ncb * 16 + c0;
    float bbv[4], muv[4], scv[4], bev[4];
    *(float4*)bbv = *(const float4*)&g2b[c];
    *(float4*)muv = *(const float4*)&smu[c];
    *(float4*)scv = *(const float4*)&ssc[c];
    *(float4*)bev = *(const float4*)&sbe[c];
#pragma unroll
    for (int mt = 0; mt < 2; ++mt) {
      const int n = n0 + mt * 16 + lr;
      const int g = mt ? g1 : g0;
      float xmv[4], xv[4], o[4];
      *(float4*)xmv = *(const float4*)&xm2[g * 128 + c];
      *(float4*)xv = *(const float4*)&x[(size_t)n * 128 + c];
      const f32x4& aa = mt ? a1 : a0;
#pragma unroll
      for (int r = 0; r < 4; ++r) {
        float v = fmaxf(aa[r] + bbv[r] - xmv[r], 0.f);
        o[r] = xv[r] + (v - muv[r]) * scv[r] + bev[r];
      }
      *(float4*)&out[(size_t)n * 128 + c] = *(float4*)o;
    }
  }
}

extern "C" void kernel_launch(void* const* d_in, const int* in_sizes, int n_in,
                              void* d_out, int out_size, void* d_ws,
                              size_t ws_size, hipStream_t stream) {
  const float* x     = (const float*)d_in[0];
  const float* W1    = (const float*)d_in[1];
  const float* b1    = (const float*)d_in[2];
  const float* W2    = (const float*)d_in[3];
  const float* b2    = (const float*)d_in[4];
  const float* W0    = (const float*)d_in[5];
  const float* b0    = (const float*)d_in[6];
  const float* g1W   = (const float*)d_in[7];
  const float* g1b   = (const float*)d_in[8];
  const float* l1W   = (const float*)d_in[9];
  const float* g2W   = (const float*)d_in[10];
  const float* g2b   = (const float*)d_in[11];
  const float* l2W   = (const float*)d_in[12];
  const float* gamma = (const float*)d_in[13];
  const float* beta  = (const float*)d_in[14];
  const int* edge_index = (const int*)d_in[15];
  const int* batch      = (const int*)d_in[16];
  const int* didx       = (const int*)d_in[17];
  float* out = (float*)d_out;

  char* ws = (char*)d_ws;
  float*  fv    = (float*) (ws + 0);           // 16,000,000 B (dead after k_pairs)
  float*  pmu   = (float*) (ws + 0);           // 2,000,384 B (reuses fv)
  float*  psq   = (float*) (ws + 2000384);     // 2,000,384 B
  ushort* ybf   = (ushort*)(ws + 16000000);    // N*64*2 = 64,000,000 B
  ushort* y2    = (ushort*)(ws + 80000000);    // N*64*2 = 64,000,000 B
  float*  sums1 = (float*) (ws + 144000000);   // 131,072 B
  float*  sums2 = (float*) (ws + 144131072);   // 131,072 B
  float*  musum = (float*) (ws + 144262144);   // 512 B
  float*  sqsum = (float*) (ws + 144262656);   // 512 B
  int*    cnt   = (int*)   (ws + 144263168);   // 2,048 B
  float*  xm1   = (float*) (ws + 144265216);   // 131,072 B
  float*  xm2   = (float*) (ws + 144396288);   // 262,144 B
  ushort* pW1   = (ushort*)(ws + 144658432);   // 8,192 B
  ushort* pW2   = (ushort*)(ws + 144666624);   // 16,384 B
  ushort* pW0   = (ushort*)(ws + 144683008);   // 32,768 B (end 144,715,776)

  hipMemsetAsync(ws + 144000000, 0, 263168, stream);  // sums1,sums2,musum,sqsum

  k_pack<<<64, 256, 0, stream>>>(g1W, g2W, W1, pW1, pW2, pW0);
  k_bounds<<<8, 64, 0, stream>>>(batch, cnt);
  k_filt<<<NBLK2, 256, 0, stream>>>(x, pW0, b1, W2, b2, fv);
  k_pairs<<<NBLK2, 256, 0, stream>>>(fv, edge_index, didx, batch, W0, b0, ybf, sums1);
  k_meanlin<64><<<NGRAPHS, 64, 0, stream>>>(sums1, cnt, l1W, xm1);
  k_ds1<<<NBLK2, 256, 0, stream>>>(ybf, batch, pW1, g1b, xm1, y2, sums2);
  k_meanlin<128><<<NGRAPHS, 128, 0, stream>>>(sums2, cnt, l2W, xm2);
  k_ds2a<<<NBLK2, 256, 0, stream>>>(y2, batch, pW2, g2b, xm2, pmu, psq);
  k_red<<<32, 256, 0, stream>>>(pmu, psq, musum, sqsum);
  k_bn<<<NBLK2, 256, 0, stream>>>(y2, batch, pW2, g2b, xm2, x, musum, sqsum,
                                  gamma, beta, out);
}

// Round 8
// 590.695 us; speedup vs baseline: 5.3568x; 1.0564x over previous
//
#include <hip/hip_runtime.h>
#include <hip/hip_bf16.h>

#define NNODES 500000
#define NEDGES 8000000
#define NGRAPHS 512
#define NFEAT 128
#define NHID 128
#define NFILT 8
#define ODIM 64
#define BN_EPS 1e-5f
#define NBLK2 3907  // ceil(NNODES/128)
#define NBLK3 7813  // ceil(NNODES/64) for k_bn

typedef __attribute__((ext_vector_type(8))) short bf16x8;
typedef __attribute__((ext_vector_type(4))) float f32x4;
#define MFMA16(a, b, c) __builtin_amdgcn_mfma_f32_16x16x32_bf16(a, b, c, 0, 0, 0)

__device__ inline ushort f2bs(float f) {
  union { __hip_bfloat16 h; ushort u; } cv;
  cv.h = __float2bfloat16(f);
  return cv.u;
}

// ---- pack W1/g1W/g2W into MFMA A-fragment layout (swapped-op: A[m=c][k]=W[k][c]) ----
__global__ void k_pack(const float* __restrict__ g1W, const float* __restrict__ g2W,
                       const float* __restrict__ W1,
                       ushort* __restrict__ pW1, ushort* __restrict__ pW2,
                       ushort* __restrict__ pW0) {
  int idx = blockIdx.x * 256 + threadIdx.x;
  if (idx < 4096) {
    int j = idx & 7, l = (idx >> 3) & 63, kb = (idx >> 9) & 1, ncb = idx >> 10;
    int k = kb * 32 + (l >> 4) * 8 + j, c = ncb * 16 + (l & 15);
    pW1[idx] = f2bs(g1W[k * 64 + c]);
  }
  if (idx < 8192) {
    int j = idx & 7, l = (idx >> 3) & 63, kb = (idx >> 9) & 1, ncb = idx >> 10;
    int k = kb * 32 + (l >> 4) * 8 + j, c = ncb * 16 + (l & 15);
    pW2[idx] = f2bs(g2W[k * 128 + c]);
  }
  if (idx < 16384) {
    int j = idx & 7, l = (idx >> 3) & 63, kb = (idx >> 9) & 3, ncb = idx >> 11;
    int k = kb * 32 + (l >> 4) * 8 + j, c = ncb * 16 + (l & 15);
    pW0[idx] = f2bs(W1[k * 128 + c]);
  }
}

// ---- Kernel 1 (MFMA): fv = relu(x@W1+b1)@W2 + b2  [N,8] f32 ----
__global__ __launch_bounds__(256) void k_filt(
    const float* __restrict__ x, const ushort* __restrict__ pW0,
    const float* __restrict__ b1, const float* __restrict__ W2,
    const float* __restrict__ b2, float* __restrict__ fv) {
  __shared__ float w2s[128 * 12];
  const int t = threadIdx.x;
  for (int i = t; i < 1024; i += 256) {
    int c = i >> 3, f = i & 7;
    w2s[c * 12 + f] = W2[i];
  }
  __syncthreads();
  const int wv = t >> 6, l = t & 63;
  const int lr = l & 15, lg = l >> 4;
  const int n0 = blockIdx.x * 128 + wv * 32;
  if (n0 >= NNODES) return;

  union { uint4 u; bf16x8 b; } bf[2][4];
#pragma unroll
  for (int mt = 0; mt < 2; ++mt)
#pragma unroll
    for (int kb = 0; kb < 4; ++kb) {
      const float* src = &x[(size_t)(n0 + mt * 16 + lr) * 128 + kb * 32 + lg * 8];
      float v[8];
      *(float4*)&v[0] = *(const float4*)src;
      *(float4*)&v[4] = *(const float4*)(src + 4);
      ushort s[8];
#pragma unroll
      for (int e = 0; e < 8; ++e) s[e] = f2bs(v[e]);
      bf[mt][kb].u = *(uint4*)s;
    }

  float pf0[8], pf1[8];
#pragma unroll
  for (int f = 0; f < 8; ++f) { pf0[f] = 0.f; pf1[f] = 0.f; }

#pragma unroll
  for (int ncb = 0; ncb < 8; ++ncb) {
    union { uint4 u; bf16x8 b; } af[4];
#pragma unroll
    for (int kb = 0; kb < 4; ++kb)
      af[kb].u = *(const uint4*)&pW0[((ncb * 4 + kb) * 64 + l) * 8];
    f32x4 a0 = (f32x4){0.f, 0.f, 0.f, 0.f};
    f32x4 a1 = (f32x4){0.f, 0.f, 0.f, 0.f};
#pragma unroll
    for (int kb = 0; kb < 4; ++kb) {
      a0 = MFMA16(af[kb].b, bf[0][kb].b, a0);
      a1 = MFMA16(af[kb].b, bf[1][kb].b, a1);
    }
    float bbv[4];
    *(float4*)bbv = *(const float4*)&b1[ncb * 16 + lg * 4];
#pragma unroll
    for (int r = 0; r < 4; ++r) {
      const int c = ncb * 16 + lg * 4 + r;
      float h0 = fmaxf(a0[r] + bbv[r], 0.f);
      float h1 = fmaxf(a1[r] + bbv[r], 0.f);
      float w20[4], w21[4];
      *(float4*)w20 = *(const float4*)&w2s[c * 12];
      *(float4*)w21 = *(const float4*)&w2s[c * 12 + 4];
#pragma unroll
      for (int f = 0; f < 4; ++f) {
        pf0[f]     = fmaf(h0, w20[f], pf0[f]);
        pf0[f + 4] = fmaf(h0, w21[f], pf0[f + 4]);
        pf1[f]     = fmaf(h1, w20[f], pf1[f]);
        pf1[f + 4] = fmaf(h1, w21[f], pf1[f + 4]);
      }
    }
  }
#pragma unroll
  for (int f = 0; f < 8; ++f) {
    pf0[f] += __shfl_xor(pf0[f], 16); pf0[f] += __shfl_xor(pf0[f], 32);
    pf1[f] += __shfl_xor(pf1[f], 16); pf1[f] += __shfl_xor(pf1[f], 32);
  }
  if (lg == 0) {
    float o0[8], o1[8];
#pragma unroll
    for (int f = 0; f < 8; ++f) {
      float bb = b2[f];
      o0[f] = pf0[f] + bb;
      o1[f] = pf1[f] + bb;
    }
    *(float4*)&fv[(size_t)(n0 + lr) * 8]          = *(float4*)&o0[0];
    *(float4*)&fv[(size_t)(n0 + lr) * 8 + 4]      = *(float4*)&o0[4];
    *(float4*)&fv[(size_t)(n0 + 16 + lr) * 8]     = *(float4*)&o1[0];
    *(float4*)&fv[(size_t)(n0 + 16 + lr) * 8 + 4] = *(float4*)&o1[4];
  }
}

// ---- cnt[g] via binary search on sorted batch ----
__global__ void k_bounds(const int* __restrict__ batch, int* __restrict__ cnt) {
  int g = blockIdx.x * 64 + threadIdx.x;
  if (g >= NGRAPHS) return;
  int lo0 = 0, hi0 = NNODES;
  while (lo0 < hi0) { int mid = (lo0 + hi0) >> 1; if (batch[mid] < g) lo0 = mid + 1; else hi0 = mid; }
  int lo1 = lo0, hi1 = NNODES;
  while (lo1 < hi1) { int mid = (lo1 + hi1) >> 1; if (batch[mid] < g + 1) lo1 = mid + 1; else hi1 = mid; }
  cnt[g] = lo1 - lo0;
}

// ------- Kernel 2: pairs + y = relu(x16@W0+b0) -> bf16; segsum1 run-length -------
__global__ __launch_bounds__(256) void k_pairs(
    const float* __restrict__ fv, const int* __restrict__ edge_index,
    const int* __restrict__ didx, const int* __restrict__ batch,
    const float* __restrict__ W0, const float* __restrict__ b0,
    ushort* __restrict__ y, float* __restrict__ sums1) {
  __shared__ float w0s[16 * 64];
  __shared__ float b0s[64];
  const int t = threadIdx.x;
  for (int i = t; i < 1024; i += 256) w0s[i] = W0[i];
  if (t < 64) b0s[t] = b0[t];
  __syncthreads();

  const int wv = t >> 6, j = t & 63;
  const int n0 = blockIdx.x * 128 + wv * 32;

  int de = 0, gg = -1, uu = 0, vvx = 0;
  if (j < 32) {
    int nn = n0 + j;
    if (nn < NNODES) { de = didx[nn]; gg = batch[nn]; }
  }
  if (j < 32 && gg >= 0) { uu = edge_index[de]; vvx = edge_index[NEDGES + de]; }

  const float bb = b0s[j];
  float acc = 0.f;
  int cur_g = -1;

#pragma unroll 4
  for (int i = 0; i < 32; ++i) {
    int g = __shfl(gg, i);
    if (g >= 0) {
      int u = __shfl(uu, i);
      int v = __shfl(vvx, i);
      int n = n0 + i;
      float nb[8], ub[8], vb[8];
      *(float4*)&nb[0] = *(const float4*)&fv[(size_t)n * 8];
      *(float4*)&nb[4] = *(const float4*)&fv[(size_t)n * 8 + 4];
      *(float4*)&ub[0] = *(const float4*)&fv[(size_t)u * 8];
      *(float4*)&ub[4] = *(const float4*)&fv[(size_t)u * 8 + 4];
      *(float4*)&vb[0] = *(const float4*)&fv[(size_t)v * 8];
      *(float4*)&vb[4] = *(const float4*)&fv[(size_t)v * 8 + 4];
      float a = bb;
#pragma unroll
      for (int f = 0; f < 8; ++f) {
        a = fmaf(nb[f], w0s[(2 * f) * 64 + j], a);
        a = fmaf(fmaxf(ub[f], vb[f]), w0s[(2 * f + 1) * 64 + j], a);
      }
      a = fmaxf(a, 0.f);
      y[(size_t)n * 64 + j] = f2bs(a);
      if (g != cur_g) {
        if (cur_g >= 0) atomicAdd(&sums1[cur_g * 64 + j], acc);
        acc = 0.f;
        cur_g = g;
      }
      acc += a;
    }
  }
  if (cur_g >= 0) atomicAdd(&sums1[cur_g * 64 + j], acc);
}

// ---------- xm = (sums/max(cnt,1)) @ LW  (D = 64 or 128) ----------
template <int D>
__global__ void k_meanlin(const float* __restrict__ sums,
                          const int* __restrict__ cnt,
                          const float* __restrict__ LW,
                          float* __restrict__ xm) {
  __shared__ float m[64];
  const int g = blockIdx.x, t = threadIdx.x;
  const float c = fmaxf((float)cnt[g], 1.f);
  if (t < 64) m[t] = sums[g * 64 + t] / c;
  __syncthreads();
  float a = 0.f;
#pragma unroll
  for (int k = 0; k < 64; ++k) a = fmaf(m[k], LW[k * D + t], a);
  xm[g * D + t] = a;
}

// ---- Kernel 4 (MFMA): y2 = relu(y@g1W + g1b - xm1[g]) bf16; segsum2 ----
__global__ __launch_bounds__(256) void k_ds1(
    const ushort* __restrict__ ybf, const int* __restrict__ batch,
    const ushort* __restrict__ pW1, const float* __restrict__ g1b,
    const float* __restrict__ xm1, ushort* __restrict__ y2,
    float* __restrict__ sums2) {
  const int t = threadIdx.x, wv = t >> 6, l = t & 63;
  const int n0 = blockIdx.x * 128 + wv * 32;
  if (n0 >= NNODES) return;
  const int lr = l & 15, lg = l >> 4;
  const int c0 = lg * 4;

  union { uint4 u; bf16x8 b; } bf[2][2];
#pragma unroll
  for (int mt = 0; mt < 2; ++mt)
#pragma unroll
    for (int kb = 0; kb < 2; ++kb)
      bf[mt][kb].u = *(const uint4*)&ybf[(size_t)(n0 + mt * 16 + lr) * 64 + kb * 32 + lg * 8];

  union { uint4 u; bf16x8 b; } af[4][2];
#pragma unroll
  for (int ncb = 0; ncb < 4; ++ncb)
#pragma unroll
    for (int kb = 0; kb < 2; ++kb)
      af[ncb][kb].u = *(const uint4*)&pW1[((ncb * 2 + kb) * 64 + l) * 8];

  f32x4 acc[2][4];
#pragma unroll
  for (int mt = 0; mt < 2; ++mt)
#pragma unroll
    for (int ncb = 0; ncb < 4; ++ncb) {
      acc[mt][ncb] = (f32x4){0.f, 0.f, 0.f, 0.f};
      acc[mt][ncb] = MFMA16(af[ncb][0].b, bf[mt][0].b, acc[mt][ncb]);
      acc[mt][ncb] = MFMA16(af[ncb][1].b, bf[mt][1].b, acc[mt][ncb]);
    }

  const int g0 = batch[n0 + lr], g1 = batch[n0 + 16 + lr];
  const int gfirst = __shfl(g0, 0);
  const bool uni = __all(g0 == gfirst) && __all(g1 == gfirst);

  float wsum[4][4];
#pragma unroll
  for (int ncb = 0; ncb < 4; ++ncb)
#pragma unroll
    for (int r = 0; r < 4; ++r) wsum[ncb][r] = 0.f;

#pragma unroll
  for (int mt = 0; mt < 2; ++mt) {
    const int n = n0 + mt * 16 + lr;
    const int g = mt ? g1 : g0;
#pragma unroll
    for (int ncb = 0; ncb < 4; ++ncb) {
      const int c = ncb * 16 + c0;
      float xmv[4], bbv[4];
      *(float4*)xmv = *(const float4*)&xm1[g * 64 + c];
      *(float4*)bbv = *(const float4*)&g1b[c];
      ushort st[4];
#pragma unroll
      for (int r = 0; r < 4; ++r) {
        float v = fmaxf(acc[mt][ncb][r] + bbv[r] - xmv[r], 0.f);
        st[r] = f2bs(v);
        if (uni) wsum[ncb][r] += v;
        else atomicAdd(&sums2[g * 64 + c + r], v);
      }
      *(ushort4*)&y2[(size_t)n * 64 + c] = *(ushort4*)st;
    }
  }
  if (uni) {
#pragma unroll
    for (int ncb = 0; ncb < 4; ++ncb)
#pragma unroll
      for (int r = 0; r < 4; ++r) {
        float w = wsum[ncb][r];
        w += __shfl_xor(w, 1); w += __shfl_xor(w, 2);
        w += __shfl_xor(w, 4); w += __shfl_xor(w, 8);
        if (lr == 0) atomicAdd(&sums2[gfirst * 64 + ncb * 16 + c0 + r], w);
      }
  }
}

// ---- Kernel 6a (MFMA, stats only): v = relu(y2@g2W + g2b - xm2[g]); BN partials ----
__global__ __launch_bounds__(256) void k_ds2a(
    const ushort* __restrict__ y2, const int* __restrict__ batch,
    const ushort* __restrict__ pW2, const float* __restrict__ g2b,
    const float* __restrict__ xm2,
    float* __restrict__ pmu, float* __restrict__ psq) {
  __shared__ float ps[4][128], pq[4][128];
  const int t = threadIdx.x, wv = t >> 6, l = t & 63;
  const int lr = l & 15, lg = l >> 4, c0 = lg * 4;
  const int n0r = blockIdx.x * 128 + wv * 32;
  const bool act = n0r < NNODES;
  const int n0 = act ? n0r : 0;

  union { uint4 u; bf16x8 b; } bf[2][2];
#pragma unroll
  for (int mt = 0; mt < 2; ++mt)
#pragma unroll
    for (int kb = 0; kb < 2; ++kb)
      bf[mt][kb].u = *(const uint4*)&y2[(size_t)(n0 + mt * 16 + lr) * 64 + kb * 32 + lg * 8];

  const int g0 = batch[n0 + lr], g1 = batch[n0 + 16 + lr];

#pragma unroll
  for (int ncb = 0; ncb < 8; ++ncb) {
    union { uint4 u; bf16x8 b; } af0, af1;
    af0.u = *(const uint4*)&pW2[((ncb * 2 + 0) * 64 + l) * 8];
    af1.u = *(const uint4*)&pW2[((ncb * 2 + 1) * 64 + l) * 8];
    f32x4 a0 = (f32x4){0.f, 0.f, 0.f, 0.f}, a1 = (f32x4){0.f, 0.f, 0.f, 0.f};
    a0 = MFMA16(af0.b, bf[0][0].b, a0); a0 = MFMA16(af1.b, bf[0][1].b, a0);
    a1 = MFMA16(af0.b, bf[1][0].b, a1); a1 = MFMA16(af1.b, bf[1][1].b, a1);

    const int c = ncb * 16 + c0;
    float xm0[4], xm1v[4], bbv[4];
    *(float4*)xm0 = *(const float4*)&xm2[g0 * 128 + c];
    *(float4*)xm1v = *(const float4*)&xm2[g1 * 128 + c];
    *(float4*)bbv = *(const float4*)&g2b[c];
    float w[4], q[4];
#pragma unroll
    for (int r = 0; r < 4; ++r) {
      float v0 = fmaxf(a0[r] + bbv[r] - xm0[r], 0.f);
      float v1 = fmaxf(a1[r] + bbv[r] - xm1v[r], 0.f);
      if (!act) { v0 = 0.f; v1 = 0.f; }
      w[r] = v0 + v1;
      q[r] = fmaf(v0, v0, v1 * v1);
    }
#pragma unroll
    for (int r = 0; r < 4; ++r) {
      float wr = w[r], qr = q[r];
      wr += __shfl_xor(wr, 1); wr += __shfl_xor(wr, 2);
      wr += __shfl_xor(wr, 4); wr += __shfl_xor(wr, 8);
      qr += __shfl_xor(qr, 1); qr += __shfl_xor(qr, 2);
      qr += __shfl_xor(qr, 4); qr += __shfl_xor(qr, 8);
      if (lr == 0) { ps[wv][c + r] = wr; pq[wv][c + r] = qr; }
    }
  }
  __syncthreads();
  if (t < 128) {
    pmu[(size_t)blockIdx.x * 128 + t] = ps[0][t] + ps[1][t] + ps[2][t] + ps[3][t];
    psq[(size_t)blockIdx.x * 128 + t] = pq[0][t] + pq[1][t] + pq[2][t] + pq[3][t];
  }
}

// ---- reduce BN partials ----
__global__ void k_red(const float* __restrict__ pmu, const float* __restrict__ psq,
                      float* __restrict__ musum, float* __restrict__ sqsum) {
  const int f = threadIdx.x & 127;
  const bool mu = threadIdx.x < 128;
  const float* src = mu ? pmu : psq;
  float s = 0.f;
  for (int b = blockIdx.x; b < NBLK2; b += 32) s += src[(size_t)b * 128 + f];
  atomicAdd(mu ? &musum[f] : &sqsum[f], s);
}

// ---- Kernel 7 (MFMA fused): recompute h (f32), stage f32 tile in LDS,
//      coalesced BN + residual writeback. 64 rows/block, wave = 16 rows. ----
__global__ __launch_bounds__(256) void k_bn(
    const ushort* __restrict__ y2, const int* __restrict__ batch,
    const ushort* __restrict__ pW2, const float* __restrict__ g2b,
    const float* __restrict__ xm2, const float* __restrict__ x,
    const float* __restrict__ musum, const float* __restrict__ sqsum,
    const float* __restrict__ gamma, const float* __restrict__ beta,
    float* __restrict__ out) {
  __shared__ float vs[64 * 132];  // h tile f32, padded row stride (33792 B)
  __shared__ float smu[128], ssc[128], sbe[128];
  const int t = threadIdx.x, wv = t >> 6, l = t & 63;
  const int lr = l & 15, lg = l >> 4, c0 = lg * 4;
  if (t < 128) {
    const float invN = 1.f / (float)NNODES;
    float m = musum[t] * invN;
    float v = sqsum[t] * invN - m * m;
    smu[t] = m;
    ssc[t] = rsqrtf(v + BN_EPS) * gamma[t];
    sbe[t] = beta[t];
  }
  const int nblk = blockIdx.x * 64;
  const int n0 = nblk + wv * 16;  // wave's 16 rows

  if (n0 < NNODES) {
    union { uint4 u; bf16x8 b; } bf[2];
#pragma unroll
    for (int kb = 0; kb < 2; ++kb)
      bf[kb].u = *(const uint4*)&y2[(size_t)(n0 + lr) * 64 + kb * 32 + lg * 8];

    const int g0 = batch[n0 + lr];
    const int row0 = wv * 16 + lr;

#pragma unroll
    for (int ncb = 0; ncb < 8; ++ncb) {
      union { uint4 u; bf16x8 b; } af0, af1;
      af0.u = *(const uint4*)&pW2[((ncb * 2 + 0) * 64 + l) * 8];
      af1.u = *(const uint4*)&pW2[((ncb * 2 + 1) * 64 + l) * 8];
      f32x4 a0 = (f32x4){0.f, 0.f, 0.f, 0.f};
      a0 = MFMA16(af0.b, bf[0].b, a0);
      a0 = MFMA16(af1.b, bf[1].b, a0);

      const int c = ncb * 16 + c0;
      float bbv[4], xm0[4], hvv[4];
      *(float4*)bbv = *(const float4*)&g2b[c];
      *(float4*)xm0 = *(const float4*)&xm2[g0 * 128 + c];
#pragma unroll
      for (int r = 0; r < 4; ++r)
        hvv[r] = fmaxf(a0[r] + bbv[r] - xm0[r], 0.f);
      *(float4*)&vs[row0 * 132 + c] = *(float4*)hvv;  // f32 — no re-quantization
    }
  }
  __syncthreads();

  // coalesced writeback: wave covers 2 rows x 128 cols per instruction
  const int rmax = NNODES - nblk;  // valid rows in this block
  for (int i = t; i < 2048; i += 256) {
    const int row = i >> 5, c4 = (i & 31) * 4;
    if (row >= rmax) break;
    const int n = nblk + row;
    float hv[4], muv[4], scv[4], bev[4], xv[4], o[4];
    *(float4*)hv = *(const float4*)&vs[row * 132 + c4];
    *(float4*)muv = *(const float4*)&smu[c4];
    *(float4*)scv = *(const float4*)&ssc[c4];
    *(float4*)bev = *(const float4*)&sbe[c4];
    *(float4*)xv = *(const float4*)&x[(size_t)n * 128 + c4];
#pragma unroll
    for (int r = 0; r < 4; ++r)
      o[r] = xv[r] + (hv[r] - muv[r]) * scv[r] + bev[r];
    *(float4*)&out[(size_t)n * 128 + c4] = *(float4*)o;
  }
}

extern "C" void kernel_launch(void* const* d_in, const int* in_sizes, int n_in,
                              void* d_out, int out_size, void* d_ws,
                              size_t ws_size, hipStream_t stream) {
  const float* x     = (const float*)d_in[0];
  const float* W1    = (const float*)d_in[1];
  const float* b1    = (const float*)d_in[2];
  const float* W2    = (const float*)d_in[3];
  const float* b2    = (const float*)d_in[4];
  const float* W0    = (const float*)d_in[5];
  const float* b0    = (const float*)d_in[6];
  const float* g1W   = (const float*)d_in[7];
  const float* g1b   = (const float*)d_in[8];
  const float* l1W   = (const float*)d_in[9];
  const float* g2W   = (const float*)d_in[10];
  const float* g2b   = (const float*)d_in[11];
  const float* l2W   = (const float*)d_in[12];
  const float* gamma = (const float*)d_in[13];
  const float* beta  = (const float*)d_in[14];
  const int* edge_index = (const int*)d_in[15];
  const int* batch      = (const int*)d_in[16];
  const int* didx       = (const int*)d_in[17];
  float* out = (float*)d_out;

  char* ws = (char*)d_ws;
  float*  fv    = (float*) (ws + 0);           // 16,000,000 B (dead after k_pairs)
  float*  pmu   = (float*) (ws + 0);           // reuses fv
  float*  psq   = (float*) (ws + 2000384);
  ushort* ybf   = (ushort*)(ws + 16000000);    // 64,000,000 B
  ushort* y2    = (ushort*)(ws + 80000000);    // 64,000,000 B
  float*  sums1 = (float*) (ws + 144000000);
  float*  sums2 = (float*) (ws + 144131072);
  float*  musum = (float*) (ws + 144262144);
  float*  sqsum = (float*) (ws + 144262656);
  int*    cnt   = (int*)   (ws + 144263168);
  float*  xm1   = (float*) (ws + 144265216);
  float*  xm2   = (float*) (ws + 144396288);
  ushort* pW1   = (ushort*)(ws + 144658432);
  ushort* pW2   = (ushort*)(ws + 144666624);
  ushort* pW0   = (ushort*)(ws + 144683008);

  hipMemsetAsync(ws + 144000000, 0, 263168, stream);

  k_pack<<<64, 256, 0, stream>>>(g1W, g2W, W1, pW1, pW2, pW0);
  k_bounds<<<8, 64, 0, stream>>>(batch, cnt);
  k_filt<<<NBLK2, 256, 0, stream>>>(x, pW0, b1, W2, b2, fv);
  k_pairs<<<NBLK2, 256, 0, stream>>>(fv, edge_index, didx, batch, W0, b0, ybf, sums1);
  k_meanlin<64><<<NGRAPHS, 64, 0, stream>>>(sums1, cnt, l1W, xm1);
  k_ds1<<<NBLK2, 256, 0, stream>>>(ybf, batch, pW1, g1b, xm1, y2, sums2);
  k_meanlin<128><<<NGRAPHS, 128, 0, stream>>>(sums2, cnt, l2W, xm2);
  k_ds2a<<<NBLK2, 256, 0, stream>>>(y2, batch, pW2, g2b, xm2, pmu, psq);
  k_red<<<32, 256, 0, stream>>>(pmu, psq, musum, sqsum);
  k_bn<<<NBLK3, 256, 0, stream>>>(y2, batch, pW2, g2b, xm2, x, musum, sqsum,
                                  gamma, beta, out);
}